// Round 1
// baseline (1998.938 us; speedup 1.0000x reference)
//
#include <hip/hip_runtime.h>
#include <float.h>
#include <math.h>

// Problem constants (B=8, N=2048, C=64, k=32, out=[64,128])
#define NB    8
#define NP    2048
#define NC    64
#define NK    32
#define KC    48      // stage-1 candidate superset size
#define NO1   64
#define NO2   128

// ---------------------------------------------------------------------------
// Kernel A0: per-point squared norm (fp32, used only for stage-1 ranking)
// ---------------------------------------------------------------------------
__global__ __launch_bounds__(256) void sq_kernel(const float* __restrict__ x,
                                                 float* __restrict__ sq) {
    int n = blockIdx.x * 256 + threadIdx.x;      // 0..16383
    const float4* r = reinterpret_cast<const float4*>(x + (size_t)n * NC);
    float a0 = 0.f, a1 = 0.f, a2 = 0.f, a3 = 0.f;
#pragma unroll
    for (int c4 = 0; c4 < 16; ++c4) {
        float4 v = r[c4];
        a0 = fmaf(v.x, v.x, a0);
        a1 = fmaf(v.y, v.y, a1);
        a2 = fmaf(v.z, v.z, a2);
        a3 = fmaf(v.w, v.w, a3);
    }
    sq[n] = (a0 + a1) + (a2 + a3);
}

// ---------------------------------------------------------------------------
// Kernel A: stage-1 kNN. Per wg: 32 queries vs all 2048 points of one batch.
// Tiled fp32 GEMM (4x4 per thread), per-query top-48 superset via
// replace-min heap maintained serially by 32 owner threads. Deterministic.
// ---------------------------------------------------------------------------
__global__ __launch_bounds__(128) void knn_stage1(const float* __restrict__ x,
                                                  const float* __restrict__ sq,
                                                  int* __restrict__ cand) {
    __shared__ float xqT[64 * 32];       // [c][q]
    __shared__ float xmT[64 * 64];       // [c][m]
    __shared__ float dt[32 * 65];        // [q][m], padded row 65
    __shared__ float sqm[64];
    __shared__ float hv[32 * 49];        // per-q min-heaps (48 slots, pad 49)
    __shared__ int   hi[32 * 49];

    const int t = threadIdx.x;
    const int b = blockIdx.x >> 6;       // 64 q-tiles per batch
    const int qt = blockIdx.x & 63;
    const int qbase = qt * 32;
    const float* xb = x + (size_t)b * NP * NC;

    // stage xqT (transposed: conflict-free column reads later)
    {
        int q = t & 31, cg = t >> 5;     // cg 0..3
        const float4* src = reinterpret_cast<const float4*>(xb + (size_t)(qbase + q) * NC);
#pragma unroll
        for (int k = 0; k < 4; ++k) {
            int c4 = cg * 4 + k;
            float4 v = src[c4];
            xqT[(c4 * 4 + 0) * 32 + q] = v.x;
            xqT[(c4 * 4 + 1) * 32 + q] = v.y;
            xqT[(c4 * 4 + 2) * 32 + q] = v.z;
            xqT[(c4 * 4 + 3) * 32 + q] = v.w;
        }
    }
    for (int s = t; s < 32 * 49; s += 128) { hv[s] = -FLT_MAX; hi[s] = 0; }
    __syncthreads();

    const int qg = t & 7, mg = t >> 3;   // 8 q-groups x 16 m-groups
    const int q0 = qg * 4, m0 = mg * 4;

    for (int mt = 0; mt < NP / 64; ++mt) {
        // stage xmT tile (transposed) + sqm
        {
            int m = t & 63, ch = t >> 6; // ch 0..1
            const float4* src = reinterpret_cast<const float4*>(xb + (size_t)(mt * 64 + m) * NC);
#pragma unroll
            for (int k = 0; k < 8; ++k) {
                int c4 = ch * 8 + k;
                float4 v = src[c4];
                xmT[(c4 * 4 + 0) * 64 + m] = v.x;
                xmT[(c4 * 4 + 1) * 64 + m] = v.y;
                xmT[(c4 * 4 + 2) * 64 + m] = v.z;
                xmT[(c4 * 4 + 3) * 64 + m] = v.w;
            }
            if (t < 64) sqm[t] = sq[(size_t)b * NP + mt * 64 + t];
        }
        __syncthreads();

        // 4x4 register-tile GEMM over K=64
        float a00=0,a01=0,a02=0,a03=0, a10=0,a11=0,a12=0,a13=0;
        float a20=0,a21=0,a22=0,a23=0, a30=0,a31=0,a32=0,a33=0;
#pragma unroll 4
        for (int c = 0; c < 64; ++c) {
            float4 av = *reinterpret_cast<const float4*>(&xqT[c * 32 + q0]);
            float4 bv = *reinterpret_cast<const float4*>(&xmT[c * 64 + m0]);
            a00 = fmaf(av.x, bv.x, a00); a01 = fmaf(av.x, bv.y, a01);
            a02 = fmaf(av.x, bv.z, a02); a03 = fmaf(av.x, bv.w, a03);
            a10 = fmaf(av.y, bv.x, a10); a11 = fmaf(av.y, bv.y, a11);
            a12 = fmaf(av.y, bv.z, a12); a13 = fmaf(av.y, bv.w, a13);
            a20 = fmaf(av.z, bv.x, a20); a21 = fmaf(av.z, bv.y, a21);
            a22 = fmaf(av.z, bv.z, a22); a23 = fmaf(av.z, bv.w, a23);
            a30 = fmaf(av.w, bv.x, a30); a31 = fmaf(av.w, bv.y, a31);
            a32 = fmaf(av.w, bv.z, a32); a33 = fmaf(av.w, bv.w, a33);
        }
        {
            float s0 = sqm[m0 + 0], s1 = sqm[m0 + 1], s2 = sqm[m0 + 2], s3 = sqm[m0 + 3];
            float* d0 = &dt[(q0 + 0) * 65 + m0];
            float* d1 = &dt[(q0 + 1) * 65 + m0];
            float* d2 = &dt[(q0 + 2) * 65 + m0];
            float* d3 = &dt[(q0 + 3) * 65 + m0];
            d0[0] = 2.f*a00 - s0; d0[1] = 2.f*a01 - s1; d0[2] = 2.f*a02 - s2; d0[3] = 2.f*a03 - s3;
            d1[0] = 2.f*a10 - s0; d1[1] = 2.f*a11 - s1; d1[2] = 2.f*a12 - s2; d1[3] = 2.f*a13 - s3;
            d2[0] = 2.f*a20 - s0; d2[1] = 2.f*a21 - s1; d2[2] = 2.f*a22 - s2; d2[3] = 2.f*a23 - s3;
            d3[0] = 2.f*a30 - s0; d3[1] = 2.f*a31 - s1; d3[2] = 2.f*a32 - s2; d3[3] = 2.f*a33 - s3;
        }
        __syncthreads();

        // owner threads merge tile candidates into per-q top-48 min-heap
        if (t < 32) {
            float* h  = &hv[t * 49];
            int*   hx = &hi[t * 49];
            const float* drow = &dt[t * 65];
            float thr = h[0];
            int mbase = mt * 64;
            for (int m = 0; m < 64; ++m) {
                float v = drow[m];
                if (v > thr) {
                    int i = 0;
                    while (1) {
                        int c = 2 * i + 1;
                        if (c >= KC) break;
                        float vc = h[c];
                        int c2 = c + 1;
                        if (c2 < KC) { float v2 = h[c2]; if (v2 < vc) { vc = v2; c = c2; } }
                        if (vc < v) { h[i] = vc; hx[i] = hx[c]; i = c; } else break;
                    }
                    h[i] = v; hx[i] = mbase + m;
                    thr = h[0];
                }
            }
        }
        __syncthreads();
    }

    if (t < 32) {
        size_t base = (size_t)((b << 11) + qbase + t) * KC;
        for (int s = 0; s < KC; ++s) cand[base + s] = hi[t * 49 + s];
    }
}

// ---------------------------------------------------------------------------
// Kernel A2: fp64 refinement — exact top-32 of the 48 candidates.
// One wave per query (4 queries / block). Deterministic shuffle reduce.
// ---------------------------------------------------------------------------
__global__ __launch_bounds__(256) void knn_refine(const float* __restrict__ x,
                                                  const int* __restrict__ cand,
                                                  int* __restrict__ idxout) {
    const int t = threadIdx.x;
    const int l = t & 63;
    const int q = blockIdx.x * 4 + (t >> 6);     // global point id
    const int b = q >> 11;
    const float* rowi = x + (size_t)q * NC;
    bool active = (l < KC);
    int myc = active ? cand[(size_t)q * KC + l] : 0;
    const float* rowm = x + ((size_t)(b << 11) + myc) * NC;

    double d0=0,d1=0,d2=0,d3=0, s0=0,s1=0,s2=0,s3=0, u0=0,u1=0,u2=0,u3=0;
#pragma unroll
    for (int c4 = 0; c4 < 16; ++c4) {
        float4 a  = reinterpret_cast<const float4*>(rowi)[c4];
        float4 bb = reinterpret_cast<const float4*>(rowm)[c4];
        double ax=a.x, ay=a.y, az=a.z, aw=a.w;
        double bx=bb.x, by=bb.y, bz=bb.z, bw=bb.w;
        d0 += ax*bx; d1 += ay*by; d2 += az*bz; d3 += aw*bw;
        s0 += ax*ax; s1 += ay*ay; s2 += az*az; s3 += aw*aw;
        u0 += bx*bx; u1 += by*by; u2 += bz*bz; u3 += bw*bw;
    }
    double dot = (d0 + d1) + (d2 + d3);
    double si  = (s0 + s1) + (s2 + s3);
    double sm  = (u0 + u1) + (u2 + u3);
    double nd  = 2.0 * dot - si - sm;

    // drop the 16 worst (smallest nd; tie -> larger index dropped first)
    for (int it = 0; it < 16; ++it) {
        double rv = active ? nd : 1e300;
        int rc = active ? myc : 0x7fffffff;
        int rl = l;
#pragma unroll
        for (int off = 32; off > 0; off >>= 1) {
            double ov = __shfl_xor(rv, off);
            int    oc = __shfl_xor(rc, off);
            int    ol = __shfl_xor(rl, off);
            if (ov < rv || (ov == rv && oc > rc)) { rv = ov; rc = oc; rl = ol; }
        }
        if (rl == l) active = false;
    }
    unsigned long long mask = __ballot(active);
    int pos = __popcll(mask & ((1ull << l) - 1ull));
    if (active) idxout[(size_t)q * NK + pos] = myc;
}

// ---------------------------------------------------------------------------
// Kernel B: fused edge-features + conv1(BN,LReLU) + conv2(BN,LReLU) + max_k.
// One wave per point; lane = output channel; weight row in registers;
// operand rows read as all-lane-broadcast float4 (global/L2 + tiny LDS).
// Uses e.W1 = x_nbr.W1a + K(o), K(o) = sum_c x_i[c]*(W1b[o][c]-W1a[o][c]).
// ---------------------------------------------------------------------------
__global__ __launch_bounds__(256) void fused_conv(const float* __restrict__ x,
        const int* __restrict__ idx32,
        const float* __restrict__ W1, const float* __restrict__ g1, const float* __restrict__ b1,
        const float* __restrict__ W2, const float* __restrict__ g2, const float* __restrict__ b2,
        float* __restrict__ out) {
    __shared__ float h1R[4][32][64];             // [wave][r][o1]
    __shared__ int   nbrL[4][32];

    const int t = threadIdx.x;
    const int w = t >> 6, l = t & 63;
    const int p = blockIdx.x * 4 + w;            // global point id
    const float* xbase = x + (size_t)(p >> 11) * (NP * NC);
    const float* xirow = x + (size_t)p * NC;
    const float invbn = 1.0f / sqrtf(1.0f + 1e-5f);

    if (l < NK) nbrL[w][l] = idx32[(size_t)p * NK + l];
    __syncthreads();

    float wreg[64];

    // preload W1a row for channel l + compute K(l)
    float k0=0,k1=0,k2=0,k3=0;
#pragma unroll
    for (int c4 = 0; c4 < 16; ++c4) {
        float4 lo = reinterpret_cast<const float4*>(W1 + (size_t)l * 128)[c4];
        float4 hi = reinterpret_cast<const float4*>(W1 + (size_t)l * 128 + 64)[c4];
        float4 xi = reinterpret_cast<const float4*>(xirow)[c4];
        wreg[c4*4+0]=lo.x; wreg[c4*4+1]=lo.y; wreg[c4*4+2]=lo.z; wreg[c4*4+3]=lo.w;
        k0 = fmaf(xi.x, hi.x - lo.x, k0);
        k1 = fmaf(xi.y, hi.y - lo.y, k1);
        k2 = fmaf(xi.z, hi.z - lo.z, k2);
        k3 = fmaf(xi.w, hi.w - lo.w, k3);
    }
    const float kv  = (k0 + k1) + (k2 + k3);
    const float s1v = g1[l] * invbn;
    const float b1v = b1[l];

    // layer 1: h1[r][l] for all 32 neighbors
    for (int r = 0; r < 32; ++r) {
        const float* xr = xbase + (size_t)nbrL[w][r] * NC;
        float a0=0,a1=0,a2=0,a3=0;
#pragma unroll
        for (int c4 = 0; c4 < 16; ++c4) {
            float4 v = reinterpret_cast<const float4*>(xr)[c4];
            a0 = fmaf(v.x, wreg[c4*4+0], a0);
            a1 = fmaf(v.y, wreg[c4*4+1], a1);
            a2 = fmaf(v.z, wreg[c4*4+2], a2);
            a3 = fmaf(v.w, wreg[c4*4+3], a3);
        }
        float hv = (((a0 + a1) + (a2 + a3)) + kv) * s1v + b1v;
        hv = hv > 0.f ? hv : 0.01f * hv;
        h1R[w][r][l] = hv;
    }
    __syncthreads();

    // layer 2 + max over k: lane handles o2 = l and o2 = l+64 sequentially
#pragma unroll 1
    for (int half = 0; half < 2; ++half) {
        const int o2 = l + 64 * half;
#pragma unroll
        for (int c4 = 0; c4 < 16; ++c4) {
            float4 wv = reinterpret_cast<const float4*>(W2 + (size_t)o2 * 64)[c4];
            wreg[c4*4+0]=wv.x; wreg[c4*4+1]=wv.y; wreg[c4*4+2]=wv.z; wreg[c4*4+3]=wv.w;
        }
        const float s2v = g2[o2] * invbn;
        const float b2v = b2[o2];
        float mx = -FLT_MAX;
        for (int r = 0; r < 32; ++r) {
            float a0=0,a1=0,a2=0,a3=0;
#pragma unroll
            for (int c4 = 0; c4 < 16; ++c4) {
                float4 v = *reinterpret_cast<const float4*>(&h1R[w][r][c4*4]);
                a0 = fmaf(v.x, wreg[c4*4+0], a0);
                a1 = fmaf(v.y, wreg[c4*4+1], a1);
                a2 = fmaf(v.z, wreg[c4*4+2], a2);
                a3 = fmaf(v.w, wreg[c4*4+3], a3);
            }
            float hv = ((a0 + a1) + (a2 + a3)) * s2v + b2v;
            hv = hv > 0.f ? hv : 0.01f * hv;
            mx = fmaxf(mx, hv);
        }
        out[(size_t)p * NO2 + o2] = mx;
    }
}

// ---------------------------------------------------------------------------
extern "C" void kernel_launch(void* const* d_in, const int* in_sizes, int n_in,
                              void* d_out, int out_size, void* d_ws, size_t ws_size,
                              hipStream_t stream) {
    const float* x  = (const float*)d_in[0];
    const float* W1 = (const float*)d_in[1];
    const float* g1 = (const float*)d_in[2];
    const float* b1 = (const float*)d_in[3];
    const float* W2 = (const float*)d_in[4];
    const float* g2 = (const float*)d_in[5];
    const float* b2 = (const float*)d_in[6];
    float* out = (float*)d_out;

    // workspace layout
    float* sqws  = (float*)d_ws;                                   // 16384 f32
    int*   candw = (int*)((char*)d_ws + 65536);                    // 16384*48 i32
    int*   idxw  = (int*)((char*)d_ws + 65536 + (size_t)NB*NP*KC*4); // 16384*32 i32

    sq_kernel  <<<NB * NP / 256, 256, 0, stream>>>(x, sqws);
    knn_stage1 <<<NB * (NP / 32), 128, 0, stream>>>(x, sqws, candw);
    knn_refine <<<NB * NP / 4,   256, 0, stream>>>(x, candw, idxw);
    fused_conv <<<NB * NP / 4,   256, 0, stream>>>(x, idxw, W1, g1, b1, W2, g2, b2, out);
}

// Round 2
// 1195.465 us; speedup vs baseline: 1.6721x; 1.6721x over previous
//
#include <hip/hip_runtime.h>
#include <float.h>
#include <math.h>

// Problem constants (B=8, N=2048, C=64, k=32, out=[64,128])
#define NB    8
#define NP    2048
#define NC    64
#define NK    32
#define KC    128     // candidates per query (4 stripes x top-32, provable superset)
#define NO1   64
#define NO2   128

// ---------------------------------------------------------------------------
// Kernel A0: per-point squared norm (fp32, used only for stage-1 ranking)
// ---------------------------------------------------------------------------
__global__ __launch_bounds__(256) void sq_kernel(const float* __restrict__ x,
                                                 float* __restrict__ sq) {
    int n = blockIdx.x * 256 + threadIdx.x;      // 0..16383
    const float4* r = reinterpret_cast<const float4*>(x + (size_t)n * NC);
    float a0 = 0.f, a1 = 0.f, a2 = 0.f, a3 = 0.f;
#pragma unroll
    for (int c4 = 0; c4 < 16; ++c4) {
        float4 v = r[c4];
        a0 = fmaf(v.x, v.x, a0);
        a1 = fmaf(v.y, v.y, a1);
        a2 = fmaf(v.z, v.z, a2);
        a3 = fmaf(v.w, v.w, a3);
    }
    sq[n] = (a0 + a1) + (a2 + a3);
}

// ---------------------------------------------------------------------------
// Kernel A: stage-1 kNN. Per wg: 32 queries vs all 2048 points of one batch.
// Tiled fp32 GEMM (4x4 per thread). Selection is fully thread-parallel:
// thread t owns (query = t&31, stripe = t>>5); maintains top-32 of its
// 512-point stripe as a u64-packed min-heap in LDS. Union of 4 stripes'
// top-32 provably contains the global top-32.
// ---------------------------------------------------------------------------
__global__ __launch_bounds__(128) void knn_stage1(const float* __restrict__ x,
                                                  const float* __restrict__ sq,
                                                  unsigned short* __restrict__ cand) {
    __shared__ float xqT[64 * 32];       // [c][q]
    __shared__ float xmT[64 * 64];       // [c][m]
    __shared__ float dt[32 * 65];        // [q][m], padded row 65
    __shared__ float sqm[64];
    __shared__ unsigned long long heap[128 * 33];  // per-thread 32-entry min-heap (+1 pad)

    const int t = threadIdx.x;
    const int b = blockIdx.x >> 6;       // 64 q-tiles per batch
    const int qt = blockIdx.x & 63;
    const int qbase = qt * 32;
    const float* xb = x + (size_t)b * NP * NC;

    // stage xqT (transposed: conflict-free column reads later)
    {
        int q = t & 31, cg = t >> 5;     // cg 0..3
        const float4* src = reinterpret_cast<const float4*>(xb + (size_t)(qbase + q) * NC);
#pragma unroll
        for (int k2 = 0; k2 < 4; ++k2) {
            int c4 = cg * 4 + k2;
            float4 v = src[c4];
            xqT[(c4 * 4 + 0) * 32 + q] = v.x;
            xqT[(c4 * 4 + 1) * 32 + q] = v.y;
            xqT[(c4 * 4 + 2) * 32 + q] = v.z;
            xqT[(c4 * 4 + 3) * 32 + q] = v.w;
        }
    }
    unsigned long long* h = &heap[t * 33];
#pragma unroll
    for (int i = 0; i < 32; ++i) h[i] = 0ULL;    // sentinel: below any real key
    unsigned long long h0 = 0ULL;                // register copy of heap-min
    __syncthreads();

    const int qg = t & 7, mg = t >> 3;   // 8 q-groups x 16 m-groups (GEMM)
    const int q0 = qg * 4, m0 = mg * 4;
    const int selq = t & 31, sels = t >> 5;  // selection: query, stripe

    for (int mt = 0; mt < NP / 64; ++mt) {
        // stage xmT tile (transposed) + sqm
        {
            int m = t & 63, ch = t >> 6; // ch 0..1
            const float4* src = reinterpret_cast<const float4*>(xb + (size_t)(mt * 64 + m) * NC);
#pragma unroll
            for (int k2 = 0; k2 < 8; ++k2) {
                int c4 = ch * 8 + k2;
                float4 v = src[c4];
                xmT[(c4 * 4 + 0) * 64 + m] = v.x;
                xmT[(c4 * 4 + 1) * 64 + m] = v.y;
                xmT[(c4 * 4 + 2) * 64 + m] = v.z;
                xmT[(c4 * 4 + 3) * 64 + m] = v.w;
            }
            if (t < 64) sqm[t] = sq[(size_t)b * NP + mt * 64 + t];
        }
        __syncthreads();

        // 4x4 register-tile GEMM over K=64
        float a00=0,a01=0,a02=0,a03=0, a10=0,a11=0,a12=0,a13=0;
        float a20=0,a21=0,a22=0,a23=0, a30=0,a31=0,a32=0,a33=0;
#pragma unroll 4
        for (int c = 0; c < 64; ++c) {
            float4 av = *reinterpret_cast<const float4*>(&xqT[c * 32 + q0]);
            float4 bv = *reinterpret_cast<const float4*>(&xmT[c * 64 + m0]);
            a00 = fmaf(av.x, bv.x, a00); a01 = fmaf(av.x, bv.y, a01);
            a02 = fmaf(av.x, bv.z, a02); a03 = fmaf(av.x, bv.w, a03);
            a10 = fmaf(av.y, bv.x, a10); a11 = fmaf(av.y, bv.y, a11);
            a12 = fmaf(av.y, bv.z, a12); a13 = fmaf(av.y, bv.w, a13);
            a20 = fmaf(av.z, bv.x, a20); a21 = fmaf(av.z, bv.y, a21);
            a22 = fmaf(av.z, bv.z, a22); a23 = fmaf(av.z, bv.w, a23);
            a30 = fmaf(av.w, bv.x, a30); a31 = fmaf(av.w, bv.y, a31);
            a32 = fmaf(av.w, bv.z, a32); a33 = fmaf(av.w, bv.w, a33);
        }
        {
            float s0 = sqm[m0 + 0], s1 = sqm[m0 + 1], s2 = sqm[m0 + 2], s3 = sqm[m0 + 3];
            float* d0 = &dt[(q0 + 0) * 65 + m0];
            float* d1 = &dt[(q0 + 1) * 65 + m0];
            float* d2 = &dt[(q0 + 2) * 65 + m0];
            float* d3 = &dt[(q0 + 3) * 65 + m0];
            d0[0] = 2.f*a00 - s0; d0[1] = 2.f*a01 - s1; d0[2] = 2.f*a02 - s2; d0[3] = 2.f*a03 - s3;
            d1[0] = 2.f*a10 - s0; d1[1] = 2.f*a11 - s1; d1[2] = 2.f*a12 - s2; d1[3] = 2.f*a13 - s3;
            d2[0] = 2.f*a20 - s0; d2[1] = 2.f*a21 - s1; d2[2] = 2.f*a22 - s2; d2[3] = 2.f*a23 - s3;
            d3[0] = 2.f*a30 - s0; d3[1] = 2.f*a31 - s1; d3[2] = 2.f*a32 - s2; d3[3] = 2.f*a33 - s3;
        }
        __syncthreads();

        // thread-parallel selection: merge my 16 values into my stripe's top-32
        {
            const float* drow = &dt[selq * 65 + sels * 16];
            const int mbase = mt * 64 + sels * 16;
#pragma unroll
            for (int j = 0; j < 16; ++j) {
                float v = drow[j];
                unsigned u = __float_as_uint(v);
                unsigned k32 = (u & 0x80000000u) ? ~u : (u | 0x80000000u);
                unsigned long long key =
                    ((unsigned long long)k32 << 32) | (unsigned)(~(mbase + j));
                if (key > h0) {
                    int i = 0;
                    while (1) {
                        int c = 2 * i + 1;
                        if (c >= 32) break;
                        unsigned long long vc = h[c];
                        int c2 = c + 1;
                        unsigned long long v2 = (c2 < 32) ? h[c2] : ~0ULL;
                        if (v2 < vc) { vc = v2; c = c2; }
                        if (vc < key) { h[i] = vc; i = c; } else break;
                    }
                    h[i] = key;
                    h0 = h[0];
                }
            }
        }
        // no sync needed: next iter's stage (xmT) + its sync orders
        // select(mt) [reads dt] before gemm(mt+1) [writes dt]
    }

    // write my stripe's 32 candidates (indices only)
    {
        size_t gq = (size_t)((b << 11) + qbase + selq);
        unsigned short* co = cand + gq * KC + sels * 32;
#pragma unroll
        for (int i = 0; i < 32; ++i)
            co[i] = (unsigned short)((~(unsigned)h[i]) & 0xFFFFu);
    }
}

// ---------------------------------------------------------------------------
// Kernel A2: fp64 refinement — exact top-32 of 128 candidates via all-pairs
// rank (order-free; max over k is permutation-invariant). One block/query.
// ---------------------------------------------------------------------------
__global__ __launch_bounds__(128) void knn_refine(const float* __restrict__ x,
                                                  const unsigned short* __restrict__ cand,
                                                  int* __restrict__ idxout) {
    __shared__ double kd[128];
    __shared__ int km[128];
    __shared__ float qrow[64];

    const int t = threadIdx.x;
    const int q = blockIdx.x;            // global point id
    const int b = q >> 11;

    if (t < 16)
        reinterpret_cast<float4*>(qrow)[t] =
            reinterpret_cast<const float4*>(x + (size_t)q * NC)[t];
    __syncthreads();

    const int m = cand[(size_t)q * KC + t];
    const float* rowm = x + ((size_t)(b << 11) + m) * NC;

    double dd0=0, dd1=0, ss0=0, ss1=0, uu0=0, uu1=0;
#pragma unroll
    for (int c4 = 0; c4 < 16; ++c4) {
        float4 a  = reinterpret_cast<const float4*>(qrow)[c4];   // LDS broadcast
        float4 bb = reinterpret_cast<const float4*>(rowm)[c4];
        double ax=a.x, ay=a.y, az=a.z, aw=a.w;
        double bx=bb.x, by=bb.y, bz=bb.z, bw=bb.w;
        dd0 += ax*bx + ay*by; dd1 += az*bz + aw*bw;
        ss0 += ax*ax + ay*ay; ss1 += az*az + aw*aw;
        uu0 += bx*bx + by*by; uu1 += bz*bz + bw*bw;
    }
    const double nd = 2.0 * (dd0 + dd1) - (ss0 + ss1) - (uu0 + uu1);

    kd[t] = nd; km[t] = m;
    __syncthreads();

    int rank = 0;
#pragma unroll 8
    for (int j = 0; j < 128; ++j) {
        double oj = kd[j]; int mj = km[j];
        rank += (oj > nd || (oj == nd && mj < m)) ? 1 : 0;
    }
    if (rank < NK) idxout[(size_t)q * NK + rank] = m;
}

// ---------------------------------------------------------------------------
// Kernel B: fused edge-features + conv1(BN,LReLU) + conv2(BN,LReLU) + max_k.
// One wave per point; lane = output channel; weight row in registers;
// operand rows read as all-lane-broadcast float4 (global/L2 + tiny LDS).
// Uses e.W1 = x_nbr.W1a + K(o), K(o) = sum_c x_i[c]*(W1b[o][c]-W1a[o][c]).
// ---------------------------------------------------------------------------
__global__ __launch_bounds__(256) void fused_conv(const float* __restrict__ x,
        const int* __restrict__ idx32,
        const float* __restrict__ W1, const float* __restrict__ g1, const float* __restrict__ b1,
        const float* __restrict__ W2, const float* __restrict__ g2, const float* __restrict__ b2,
        float* __restrict__ out) {
    __shared__ float h1R[4][32][64];             // [wave][r][o1]
    __shared__ int   nbrL[4][32];

    const int t = threadIdx.x;
    const int w = t >> 6, l = t & 63;
    const int p = blockIdx.x * 4 + w;            // global point id
    const float* xbase = x + (size_t)(p >> 11) * (NP * NC);
    const float* xirow = x + (size_t)p * NC;
    const float invbn = 1.0f / sqrtf(1.0f + 1e-5f);

    if (l < NK) nbrL[w][l] = idx32[(size_t)p * NK + l];
    __syncthreads();

    float wreg[64];

    // preload W1a row for channel l + compute K(l)
    float k0=0,k1=0,k2=0,k3=0;
#pragma unroll
    for (int c4 = 0; c4 < 16; ++c4) {
        float4 lo = reinterpret_cast<const float4*>(W1 + (size_t)l * 128)[c4];
        float4 hi = reinterpret_cast<const float4*>(W1 + (size_t)l * 128 + 64)[c4];
        float4 xi = reinterpret_cast<const float4*>(xirow)[c4];
        wreg[c4*4+0]=lo.x; wreg[c4*4+1]=lo.y; wreg[c4*4+2]=lo.z; wreg[c4*4+3]=lo.w;
        k0 = fmaf(xi.x, hi.x - lo.x, k0);
        k1 = fmaf(xi.y, hi.y - lo.y, k1);
        k2 = fmaf(xi.z, hi.z - lo.z, k2);
        k3 = fmaf(xi.w, hi.w - lo.w, k3);
    }
    const float kv  = (k0 + k1) + (k2 + k3);
    const float s1v = g1[l] * invbn;
    const float b1v = b1[l];

    // layer 1: h1[r][l] for all 32 neighbors
    for (int r = 0; r < 32; ++r) {
        const float* xr = xbase + (size_t)nbrL[w][r] * NC;
        float a0=0,a1=0,a2=0,a3=0;
#pragma unroll
        for (int c4 = 0; c4 < 16; ++c4) {
            float4 v = reinterpret_cast<const float4*>(xr)[c4];
            a0 = fmaf(v.x, wreg[c4*4+0], a0);
            a1 = fmaf(v.y, wreg[c4*4+1], a1);
            a2 = fmaf(v.z, wreg[c4*4+2], a2);
            a3 = fmaf(v.w, wreg[c4*4+3], a3);
        }
        float hv = (((a0 + a1) + (a2 + a3)) + kv) * s1v + b1v;
        hv = hv > 0.f ? hv : 0.01f * hv;
        h1R[w][r][l] = hv;
    }
    __syncthreads();

    // layer 2 + max over k: lane handles o2 = l and o2 = l+64 sequentially
#pragma unroll 1
    for (int half = 0; half < 2; ++half) {
        const int o2 = l + 64 * half;
#pragma unroll
        for (int c4 = 0; c4 < 16; ++c4) {
            float4 wv = reinterpret_cast<const float4*>(W2 + (size_t)o2 * 64)[c4];
            wreg[c4*4+0]=wv.x; wreg[c4*4+1]=wv.y; wreg[c4*4+2]=wv.z; wreg[c4*4+3]=wv.w;
        }
        const float s2v = g2[o2] * invbn;
        const float b2v = b2[o2];
        float mx = -FLT_MAX;
        for (int r = 0; r < 32; ++r) {
            float a0=0,a1=0,a2=0,a3=0;
#pragma unroll
            for (int c4 = 0; c4 < 16; ++c4) {
                float4 v = *reinterpret_cast<const float4*>(&h1R[w][r][c4*4]);
                a0 = fmaf(v.x, wreg[c4*4+0], a0);
                a1 = fmaf(v.y, wreg[c4*4+1], a1);
                a2 = fmaf(v.z, wreg[c4*4+2], a2);
                a3 = fmaf(v.w, wreg[c4*4+3], a3);
            }
            float hv = ((a0 + a1) + (a2 + a3)) * s2v + b2v;
            hv = hv > 0.f ? hv : 0.01f * hv;
            mx = fmaxf(mx, hv);
        }
        out[(size_t)p * NO2 + o2] = mx;
    }
}

// ---------------------------------------------------------------------------
extern "C" void kernel_launch(void* const* d_in, const int* in_sizes, int n_in,
                              void* d_out, int out_size, void* d_ws, size_t ws_size,
                              hipStream_t stream) {
    const float* x  = (const float*)d_in[0];
    const float* W1 = (const float*)d_in[1];
    const float* g1 = (const float*)d_in[2];
    const float* b1 = (const float*)d_in[3];
    const float* W2 = (const float*)d_in[4];
    const float* g2 = (const float*)d_in[5];
    const float* b2 = (const float*)d_in[6];
    float* out = (float*)d_out;

    // workspace layout
    float*          sqws  = (float*)d_ws;                                  // 16384 f32 (64 KB)
    unsigned short* candw = (unsigned short*)((char*)d_ws + 65536);        // 16384*128 u16 (4 MB)
    int*            idxw  = (int*)((char*)d_ws + 65536 + (size_t)NB*NP*KC*2); // 16384*32 i32 (2 MB)

    sq_kernel  <<<NB * NP / 256, 256, 0, stream>>>(x, sqws);
    knn_stage1 <<<NB * (NP / 32), 128, 0, stream>>>(x, sqws, candw);
    knn_refine <<<NB * NP,       128, 0, stream>>>(x, candw, idxw);
    fused_conv <<<NB * NP / 4,   256, 0, stream>>>(x, idxw, W1, g1, b1, W2, g2, b2, out);
}

// Round 3
// 717.302 us; speedup vs baseline: 2.7867x; 1.6666x over previous
//
#include <hip/hip_runtime.h>
#include <float.h>
#include <math.h>

// Problem constants (B=8, N=2048, C=64, k=32, out=[64,128])
#define NB    8
#define NP    2048
#define NC    64
#define NK    32
#define KC    128     // candidates per query (4 stripes x top-32, provable superset)
#define NO2   128

typedef __attribute__((ext_vector_type(8))) short short8v;   // 8 bf16 (4 VGPRs)
typedef __attribute__((ext_vector_type(4))) float f32x4;

__device__ __forceinline__ unsigned short f2bf(float f) {    // RNE f32->bf16
    unsigned u = __float_as_uint(f);
    return (unsigned short)((u + 0x7fffu + ((u >> 16) & 1u)) >> 16);
}

// ---------------------------------------------------------------------------
// Kernel A0: per-point squared norm (fp32, stage-1 ranking only)
// ---------------------------------------------------------------------------
__global__ __launch_bounds__(256) void sq_kernel(const float* __restrict__ x,
                                                 float* __restrict__ sq) {
    int n = blockIdx.x * 256 + threadIdx.x;
    const float4* r = reinterpret_cast<const float4*>(x + (size_t)n * NC);
    float a0 = 0.f, a1 = 0.f, a2 = 0.f, a3 = 0.f;
#pragma unroll
    for (int c4 = 0; c4 < 16; ++c4) {
        float4 v = r[c4];
        a0 = fmaf(v.x, v.x, a0);
        a1 = fmaf(v.y, v.y, a1);
        a2 = fmaf(v.z, v.z, a2);
        a3 = fmaf(v.w, v.w, a3);
    }
    sq[n] = (a0 + a1) + (a2 + a3);
}

// ---------------------------------------------------------------------------
// Kernel P: prep — Ys = (x.W1a^T)*s1, Ks = (x.(W1b-W1a)^T)*s1 + b1 (fp32),
// plus W2 packed to bf16. One wave per 16 points; lane = output channel.
// ---------------------------------------------------------------------------
__global__ __launch_bounds__(256) void prep_kernel(
    const float* __restrict__ x, const float* __restrict__ W1,
    const float* __restrict__ g1, const float* __restrict__ b1,
    const float* __restrict__ W2,
    float* __restrict__ Ys, float* __restrict__ Ks,
    unsigned short* __restrict__ W2bf)
{
    const int t = threadIdx.x;
    const int w = t >> 6, l = t & 63;
    const float invbn = 1.0f / sqrtf(1.0f + 1e-5f);

    // block 0: pack W2 (128x64 f32) -> bf16, one row per thread
    if (blockIdx.x == 0 && t < 128) {
        const float4* src = reinterpret_cast<const float4*>(W2 + (size_t)t * 64);
        ushort4* dst = reinterpret_cast<ushort4*>(W2bf + (size_t)t * 64);
#pragma unroll
        for (int i = 0; i < 16; ++i) {
            float4 v = src[i];
            ushort4 pk = { f2bf(v.x), f2bf(v.y), f2bf(v.z), f2bf(v.w) };
            dst[i] = pk;
        }
    }

    float was[64], wds[64];
    const float s1v = g1[l] * invbn;
    const float b1v = b1[l];
#pragma unroll
    for (int c4 = 0; c4 < 16; ++c4) {
        float4 lo = reinterpret_cast<const float4*>(W1 + (size_t)l * 128)[c4];
        float4 hi = reinterpret_cast<const float4*>(W1 + (size_t)l * 128 + 64)[c4];
        was[c4*4+0] = lo.x * s1v; was[c4*4+1] = lo.y * s1v;
        was[c4*4+2] = lo.z * s1v; was[c4*4+3] = lo.w * s1v;
        wds[c4*4+0] = (hi.x - lo.x) * s1v; wds[c4*4+1] = (hi.y - lo.y) * s1v;
        wds[c4*4+2] = (hi.z - lo.z) * s1v; wds[c4*4+3] = (hi.w - lo.w) * s1v;
    }

    const int pbase = (blockIdx.x * 4 + w) * 16;
#pragma unroll 1
    for (int i = 0; i < 16; ++i) {
        const int p = pbase + i;
        const float* xr = x + (size_t)p * NC;
        float y0 = 0.f, y1 = 0.f, k0 = 0.f, k1 = 0.f;
#pragma unroll
        for (int c4 = 0; c4 < 16; ++c4) {
            float4 v = reinterpret_cast<const float4*>(xr)[c4];
            y0 = fmaf(v.x, was[c4*4+0], y0); y1 = fmaf(v.y, was[c4*4+1], y1);
            y0 = fmaf(v.z, was[c4*4+2], y0); y1 = fmaf(v.w, was[c4*4+3], y1);
            k0 = fmaf(v.x, wds[c4*4+0], k0); k1 = fmaf(v.y, wds[c4*4+1], k1);
            k0 = fmaf(v.z, wds[c4*4+2], k0); k1 = fmaf(v.w, wds[c4*4+3], k1);
        }
        Ys[(size_t)p * NC + l] = y0 + y1;
        Ks[(size_t)p * NC + l] = (k0 + k1) + b1v;
    }
}

// ---------------------------------------------------------------------------
// Kernel A: stage-1 kNN — fp32 tiled GEMM + REGISTER top-32 per (q, stripe).
// Keys are u64 (sortable-f32 dist << 32 | ~idx): unique, so replace-min is a
// branch-free unrolled eq/select+min pass. No selection LDS.
// ---------------------------------------------------------------------------
__global__ __launch_bounds__(128) void knn_stage1(const float* __restrict__ x,
                                                  const float* __restrict__ sq,
                                                  unsigned short* __restrict__ cand) {
    __shared__ float xqT[64 * 32];       // [c][q]
    __shared__ float xmT[64 * 64];       // [c][m]
    __shared__ float dt[32 * 65];        // [q][m], padded
    __shared__ float sqm[64];

    const int t = threadIdx.x;
    const int b = blockIdx.x >> 6;
    const int qt = blockIdx.x & 63;
    const int qbase = qt * 32;
    const float* xb = x + (size_t)b * NP * NC;

    {
        int q = t & 31, cg = t >> 5;
        const float4* src = reinterpret_cast<const float4*>(xb + (size_t)(qbase + q) * NC);
#pragma unroll
        for (int k2 = 0; k2 < 4; ++k2) {
            int c4 = cg * 4 + k2;
            float4 v = src[c4];
            xqT[(c4 * 4 + 0) * 32 + q] = v.x;
            xqT[(c4 * 4 + 1) * 32 + q] = v.y;
            xqT[(c4 * 4 + 2) * 32 + q] = v.z;
            xqT[(c4 * 4 + 3) * 32 + q] = v.w;
        }
    }

    unsigned long long kreg[32];
#pragma unroll
    for (int i = 0; i < 32; ++i) kreg[i] = (unsigned long long)i;  // distinct sentinels
    unsigned long long mn = 0ULL;

    __syncthreads();

    const int qg = t & 7, mg = t >> 3;
    const int q0 = qg * 4, m0 = mg * 4;
    const int selq = t & 31, sels = t >> 5;

    for (int mt = 0; mt < NP / 64; ++mt) {
        {
            int m = t & 63, ch = t >> 6;
            const float4* src = reinterpret_cast<const float4*>(xb + (size_t)(mt * 64 + m) * NC);
#pragma unroll
            for (int k2 = 0; k2 < 8; ++k2) {
                int c4 = ch * 8 + k2;
                float4 v = src[c4];
                xmT[(c4 * 4 + 0) * 64 + m] = v.x;
                xmT[(c4 * 4 + 1) * 64 + m] = v.y;
                xmT[(c4 * 4 + 2) * 64 + m] = v.z;
                xmT[(c4 * 4 + 3) * 64 + m] = v.w;
            }
            if (t < 64) sqm[t] = sq[(size_t)b * NP + mt * 64 + t];
        }
        __syncthreads();

        float a00=0,a01=0,a02=0,a03=0, a10=0,a11=0,a12=0,a13=0;
        float a20=0,a21=0,a22=0,a23=0, a30=0,a31=0,a32=0,a33=0;
#pragma unroll 4
        for (int c = 0; c < 64; ++c) {
            float4 av = *reinterpret_cast<const float4*>(&xqT[c * 32 + q0]);
            float4 bv = *reinterpret_cast<const float4*>(&xmT[c * 64 + m0]);
            a00 = fmaf(av.x, bv.x, a00); a01 = fmaf(av.x, bv.y, a01);
            a02 = fmaf(av.x, bv.z, a02); a03 = fmaf(av.x, bv.w, a03);
            a10 = fmaf(av.y, bv.x, a10); a11 = fmaf(av.y, bv.y, a11);
            a12 = fmaf(av.y, bv.z, a12); a13 = fmaf(av.y, bv.w, a13);
            a20 = fmaf(av.z, bv.x, a20); a21 = fmaf(av.z, bv.y, a21);
            a22 = fmaf(av.z, bv.z, a22); a23 = fmaf(av.z, bv.w, a23);
            a30 = fmaf(av.w, bv.x, a30); a31 = fmaf(av.w, bv.y, a31);
            a32 = fmaf(av.w, bv.z, a32); a33 = fmaf(av.w, bv.w, a33);
        }
        {
            float s0 = sqm[m0 + 0], s1 = sqm[m0 + 1], s2 = sqm[m0 + 2], s3 = sqm[m0 + 3];
            float* d0 = &dt[(q0 + 0) * 65 + m0];
            float* d1 = &dt[(q0 + 1) * 65 + m0];
            float* d2 = &dt[(q0 + 2) * 65 + m0];
            float* d3 = &dt[(q0 + 3) * 65 + m0];
            d0[0] = 2.f*a00 - s0; d0[1] = 2.f*a01 - s1; d0[2] = 2.f*a02 - s2; d0[3] = 2.f*a03 - s3;
            d1[0] = 2.f*a10 - s0; d1[1] = 2.f*a11 - s1; d1[2] = 2.f*a12 - s2; d1[3] = 2.f*a13 - s3;
            d2[0] = 2.f*a20 - s0; d2[1] = 2.f*a21 - s1; d2[2] = 2.f*a22 - s2; d2[3] = 2.f*a23 - s3;
            d3[0] = 2.f*a30 - s0; d3[1] = 2.f*a31 - s1; d3[2] = 2.f*a32 - s2; d3[3] = 2.f*a33 - s3;
        }
        __syncthreads();

        // register replace-min selection over my 16 values
        {
            const float* drow = &dt[selq * 65 + sels * 16];
            const int mbase = mt * 64 + sels * 16;
#pragma unroll 1
            for (int j = 0; j < 16; ++j) {
                float v = drow[j];
                unsigned u = __float_as_uint(v);
                unsigned k32 = u ^ (0x80000000u | (unsigned)((int)u >> 31));
                unsigned long long key =
                    ((unsigned long long)k32 << 32) | (unsigned)(~(mbase + j));
                if (key > mn) {
                    unsigned long long nmn0 = ~0ULL, nmn1 = ~0ULL;
#pragma unroll
                    for (int i = 0; i < 32; i += 2) {
                        kreg[i]   = (kreg[i]   == mn) ? key : kreg[i];
                        kreg[i+1] = (kreg[i+1] == mn) ? key : kreg[i+1];
                        nmn0 = kreg[i]   < nmn0 ? kreg[i]   : nmn0;
                        nmn1 = kreg[i+1] < nmn1 ? kreg[i+1] : nmn1;
                    }
                    mn = nmn0 < nmn1 ? nmn0 : nmn1;
                }
            }
        }
        // no extra sync: next tile's stage+sync orders select(mt) before gemm(mt+1)
    }

    {
        size_t gq = (size_t)((b << 11) + qbase + selq);
        unsigned short* co = cand + gq * KC + sels * 32;
#pragma unroll
        for (int i = 0; i < 32; ++i)
            co[i] = (unsigned short)((~(unsigned)kreg[i]) & 0xFFFFu);
    }
}

// ---------------------------------------------------------------------------
// Kernel A2: fp64 refinement — exact top-32 of 128 candidates via all-pairs
// rank (order-free). One block per query.
// ---------------------------------------------------------------------------
__global__ __launch_bounds__(128) void knn_refine(const float* __restrict__ x,
                                                  const unsigned short* __restrict__ cand,
                                                  int* __restrict__ idxout) {
    __shared__ double kd[128];
    __shared__ int km[128];
    __shared__ float qrow[64];

    const int t = threadIdx.x;
    const int q = blockIdx.x;
    const int b = q >> 11;

    if (t < 16)
        reinterpret_cast<float4*>(qrow)[t] =
            reinterpret_cast<const float4*>(x + (size_t)q * NC)[t];
    __syncthreads();

    const int m = cand[(size_t)q * KC + t];
    const float* rowm = x + ((size_t)(b << 11) + m) * NC;

    double dd0=0, dd1=0, ss0=0, ss1=0, uu0=0, uu1=0;
#pragma unroll
    for (int c4 = 0; c4 < 16; ++c4) {
        float4 a  = reinterpret_cast<const float4*>(qrow)[c4];
        float4 bb = reinterpret_cast<const float4*>(rowm)[c4];
        double ax=a.x, ay=a.y, az=a.z, aw=a.w;
        double bx=bb.x, by=bb.y, bz=bb.z, bw=bb.w;
        dd0 += ax*bx + ay*by; dd1 += az*bz + aw*bw;
        ss0 += ax*ax + ay*ay; ss1 += az*az + aw*aw;
        uu0 += bx*bx + by*by; uu1 += bz*bz + bw*bw;
    }
    const double nd = 2.0 * (dd0 + dd1) - (ss0 + ss1) - (uu0 + uu1);

    kd[t] = nd; km[t] = m;
    __syncthreads();

    int rank = 0;
#pragma unroll 8
    for (int j = 0; j < 128; ++j) {
        double oj = kd[j]; int mj = km[j];
        rank += (oj > nd || (oj == nd && mj < m)) ? 1 : 0;
    }
    if (rank < NK) idxout[(size_t)q * NK + rank] = m;
}

// ---------------------------------------------------------------------------
// Kernel B: gather Ys[nbr]+Ks[i] -> LReLU -> bf16 h1 tile (LDS, pad-72) ->
// layer-2 via mfma_f32_16x16x32_bf16 (M=32 nbrs, N=128 out, K=64) ->
// BN+LReLU+max-over-k in epilogue. One wave per point, 4 waves/block.
// ---------------------------------------------------------------------------
__global__ __launch_bounds__(256) void conv2_kernel(
    const float* __restrict__ Ys, const float* __restrict__ Ks,
    const unsigned short* __restrict__ W2bf,
    const float* __restrict__ g2, const float* __restrict__ b2,
    const int* __restrict__ idx32, float* __restrict__ out)
{
    __shared__ short w2l[128 * 72];      // W2 bf16, rows padded to 72
    __shared__ short h1l[4][32 * 72];    // per-wave h1 tile, rows padded to 72

    const int t = threadIdx.x;
    const int w = t >> 6, l = t & 63;
    const int g = l >> 4, li = l & 15;
    const int p = blockIdx.x * 4 + w;
    const int b = p >> 11;
    const float invbn = 1.0f / sqrtf(1.0f + 1e-5f);

    // stage W2bf -> LDS (2 threads per row)
    {
        const int r = t >> 1, half = t & 1;
        const uint4* src = reinterpret_cast<const uint4*>(W2bf + (size_t)r * 64 + half * 32);
        uint4* dst = reinterpret_cast<uint4*>(&w2l[r * 72 + half * 32]);
#pragma unroll
        for (int i = 0; i < 4; ++i) dst[i] = src[i];
    }

    // per-lane preloads
    float g2r[8], b2r[8];
#pragma unroll
    for (int nt = 0; nt < 8; ++nt) {
        g2r[nt] = g2[nt * 16 + li] * invbn;
        b2r[nt] = b2[nt * 16 + li];
    }
    const float4 ksv = reinterpret_cast<const float4*>(Ks + (size_t)p * NC)[li];

    int jarr[8];
#pragma unroll
    for (int r2 = 0; r2 < 8; ++r2)
        jarr[r2] = idx32[(size_t)p * NK + r2 * 4 + g];

    // gather + add Ks + LReLU + bf16 pack: lane group g handles rows r2*4+g,
    // lane li handles channels li*4..li*4+3
#pragma unroll
    for (int r2 = 0; r2 < 8; ++r2) {
        const int r = r2 * 4 + g;
        const float4 v = reinterpret_cast<const float4*>(
            Ys + ((size_t)(b << 11) + jarr[r2]) * NC)[li];
        float h0 = v.x + ksv.x; h0 = h0 > 0.f ? h0 : 0.01f * h0;
        float h1 = v.y + ksv.y; h1 = h1 > 0.f ? h1 : 0.01f * h1;
        float h2 = v.z + ksv.z; h2 = h2 > 0.f ? h2 : 0.01f * h2;
        float h3 = v.w + ksv.w; h3 = h3 > 0.f ? h3 : 0.01f * h3;
        ushort4 pk = { f2bf(h0), f2bf(h1), f2bf(h2), f2bf(h3) };
        *reinterpret_cast<ushort4*>(&h1l[w][r * 72 + li * 4]) = pk;
    }
    __syncthreads();

    // A fragments: lane holds h1 row (mt*16+li), channels kt*32+8g..+7
    short8v a[2][2];
#pragma unroll
    for (int mt2 = 0; mt2 < 2; ++mt2)
#pragma unroll
        for (int kt = 0; kt < 2; ++kt)
            a[mt2][kt] = *reinterpret_cast<const short8v*>(
                &h1l[w][(mt2 * 16 + li) * 72 + kt * 32 + g * 8]);

#pragma unroll 1
    for (int nt = 0; nt < 8; ++nt) {
        // B fragments: lane holds W2 row (nt*16+li), channels kt*32+8g..+7
        short8v b0 = *reinterpret_cast<const short8v*>(&w2l[(nt * 16 + li) * 72 + g * 8]);
        short8v b1 = *reinterpret_cast<const short8v*>(&w2l[(nt * 16 + li) * 72 + 32 + g * 8]);
        f32x4 acc0 = {0.f, 0.f, 0.f, 0.f};
        f32x4 acc1 = {0.f, 0.f, 0.f, 0.f};
        acc0 = __builtin_amdgcn_mfma_f32_16x16x32_bf16(a[0][0], b0, acc0, 0, 0, 0);
        acc0 = __builtin_amdgcn_mfma_f32_16x16x32_bf16(a[0][1], b1, acc0, 0, 0, 0);
        acc1 = __builtin_amdgcn_mfma_f32_16x16x32_bf16(a[1][0], b0, acc1, 0, 0, 0);
        acc1 = __builtin_amdgcn_mfma_f32_16x16x32_bf16(a[1][1], b1, acc1, 0, 0, 0);

        const float s2v = g2r[nt], c2v = b2r[nt];
        float mx = -FLT_MAX;
#pragma unroll
        for (int r = 0; r < 4; ++r) {
            float hA = acc0[r] * s2v + c2v; hA = hA > 0.f ? hA : 0.01f * hA;
            float hB = acc1[r] * s2v + c2v; hB = hB > 0.f ? hB : 0.01f * hB;
            mx = fmaxf(mx, fmaxf(hA, hB));
        }
        mx = fmaxf(mx, __shfl_xor(mx, 16));
        mx = fmaxf(mx, __shfl_xor(mx, 32));
        if (l < 16) out[(size_t)p * NO2 + nt * 16 + l] = mx;
    }
}

// ---------------------------------------------------------------------------
extern "C" void kernel_launch(void* const* d_in, const int* in_sizes, int n_in,
                              void* d_out, int out_size, void* d_ws, size_t ws_size,
                              hipStream_t stream) {
    const float* x  = (const float*)d_in[0];
    const float* W1 = (const float*)d_in[1];
    const float* g1 = (const float*)d_in[2];
    const float* b1 = (const float*)d_in[3];
    const float* W2 = (const float*)d_in[4];
    const float* g2 = (const float*)d_in[5];
    const float* b2 = (const float*)d_in[6];
    float* out = (float*)d_out;

    // workspace layout (≈14.1 MB)
    char* ws = (char*)d_ws;
    float*          sqws  = (float*)(ws);                      // 64 KB
    unsigned short* candw = (unsigned short*)(ws + 65536);     // 4 MB
    int*            idxw  = (int*)(ws + 4259840);              // 2 MB
    float*          Ysw   = (float*)(ws + 6356992);            // 4 MB
    float*          Ksw   = (float*)(ws + 10551296);           // 4 MB
    unsigned short* w2bfw = (unsigned short*)(ws + 14745600);  // 16 KB

    prep_kernel<<<256,          256, 0, stream>>>(x, W1, g1, b1, W2, Ysw, Ksw, w2bfw);
    sq_kernel  <<<NB * NP / 256, 256, 0, stream>>>(x, sqws);
    knn_stage1 <<<NB * (NP / 32), 128, 0, stream>>>(x, sqws, candw);
    knn_refine <<<NB * NP,       128, 0, stream>>>(x, candw, idxw);
    conv2_kernel<<<NB * NP / 4,  256, 0, stream>>>(Ysw, Ksw, w2bfw, g2, b2, idxw, out);
}

// Round 4
// 201.043 us; speedup vs baseline: 9.9428x; 3.5679x over previous
//
#include <hip/hip_runtime.h>
#include <hip/hip_fp16.h>
#include <float.h>
#include <math.h>

// Problem constants (B=8, N=2048, C=64, k=32, out=[64,128])
#define NB    8
#define NP    2048
#define NC    64
#define NK    32
#define NCAND 80      // candidate buffer per query
#define RSEL  48      // rank-threshold for superset selection
#define NO2   128

typedef unsigned short ushort_t;
typedef __attribute__((ext_vector_type(8))) short short8v;   // 8 bf16 (4 VGPRs)
typedef __attribute__((ext_vector_type(4))) float f32x4;

__device__ __forceinline__ unsigned short f2bf(float f) {    // RNE f32->bf16
    unsigned u = __float_as_uint(f);
    return (unsigned short)((u + 0x7fffu + ((u >> 16) & 1u)) >> 16);
}

// sortable-u16 key from raw fp16 bits (ascending distance -> ascending key)
__device__ __forceinline__ unsigned h2key(unsigned u) {
    return (u & 0x8000u) ? (u ^ 0xFFFFu) : (u | 0x8000u);
}

// ---------------------------------------------------------------------------
// Kernel 0: x -> bf16 copy + exact fp32 squared norms. 8 threads/point.
// ---------------------------------------------------------------------------
__global__ __launch_bounds__(256) void xcvt_sq_kernel(const float* __restrict__ x,
                                                      unsigned short* __restrict__ xbf,
                                                      float* __restrict__ sqf) {
    int gid = blockIdx.x * 256 + threadIdx.x;
    int p = gid >> 3, c8 = (gid & 7) * 8;
    const float4* src = reinterpret_cast<const float4*>(x + (size_t)p * NC + c8);
    float4 v0 = src[0], v1 = src[1];
    ushort4 pk0 = { f2bf(v0.x), f2bf(v0.y), f2bf(v0.z), f2bf(v0.w) };
    ushort4 pk1 = { f2bf(v1.x), f2bf(v1.y), f2bf(v1.z), f2bf(v1.w) };
    ushort4* dst = reinterpret_cast<ushort4*>(xbf + (size_t)p * NC + c8);
    dst[0] = pk0; dst[1] = pk1;
    float s = v0.x*v0.x + v0.y*v0.y + v0.z*v0.z + v0.w*v0.w
            + v1.x*v1.x + v1.y*v1.y + v1.z*v1.z + v1.w*v1.w;
    s += __shfl_xor(s, 1); s += __shfl_xor(s, 2); s += __shfl_xor(s, 4);
    if ((threadIdx.x & 7) == 0) sqf[p] = s;
}

// ---------------------------------------------------------------------------
// Kernel P: prep — Ys = (x.W1a^T)*s1, Ks = (x.(W1b-W1a)^T)*s1 + b1 (fp32),
// plus W2 packed to bf16. One wave per 16 points; lane = output channel.
// ---------------------------------------------------------------------------
__global__ __launch_bounds__(256) void prep_kernel(
    const float* __restrict__ x, const float* __restrict__ W1,
    const float* __restrict__ g1, const float* __restrict__ b1,
    const float* __restrict__ W2,
    float* __restrict__ Ys, float* __restrict__ Ks,
    unsigned short* __restrict__ W2bf)
{
    const int t = threadIdx.x;
    const int w = t >> 6, l = t & 63;
    const float invbn = 1.0f / sqrtf(1.0f + 1e-5f);

    if (blockIdx.x == 0 && t < 128) {
        const float4* src = reinterpret_cast<const float4*>(W2 + (size_t)t * 64);
        ushort4* dst = reinterpret_cast<ushort4*>(W2bf + (size_t)t * 64);
#pragma unroll
        for (int i = 0; i < 16; ++i) {
            float4 v = src[i];
            ushort4 pk = { f2bf(v.x), f2bf(v.y), f2bf(v.z), f2bf(v.w) };
            dst[i] = pk;
        }
    }

    float was[64], wds[64];
    const float s1v = g1[l] * invbn;
    const float b1v = b1[l];
#pragma unroll
    for (int c4 = 0; c4 < 16; ++c4) {
        float4 lo = reinterpret_cast<const float4*>(W1 + (size_t)l * 128)[c4];
        float4 hi = reinterpret_cast<const float4*>(W1 + (size_t)l * 128 + 64)[c4];
        was[c4*4+0] = lo.x * s1v; was[c4*4+1] = lo.y * s1v;
        was[c4*4+2] = lo.z * s1v; was[c4*4+3] = lo.w * s1v;
        wds[c4*4+0] = (hi.x - lo.x) * s1v; wds[c4*4+1] = (hi.y - lo.y) * s1v;
        wds[c4*4+2] = (hi.z - lo.z) * s1v; wds[c4*4+3] = (hi.w - lo.w) * s1v;
    }

    const int pbase = (blockIdx.x * 4 + w) * 16;
#pragma unroll 1
    for (int i = 0; i < 16; ++i) {
        const int p = pbase + i;
        const float* xr = x + (size_t)p * NC;
        float y0 = 0.f, y1 = 0.f, k0 = 0.f, k1 = 0.f;
#pragma unroll
        for (int c4 = 0; c4 < 16; ++c4) {
            float4 v = reinterpret_cast<const float4*>(xr)[c4];
            y0 = fmaf(v.x, was[c4*4+0], y0); y1 = fmaf(v.y, was[c4*4+1], y1);
            y0 = fmaf(v.z, was[c4*4+2], y0); y1 = fmaf(v.w, was[c4*4+3], y1);
            k0 = fmaf(v.x, wds[c4*4+0], k0); k1 = fmaf(v.y, wds[c4*4+1], k1);
            k0 = fmaf(v.z, wds[c4*4+2], k0); k1 = fmaf(v.w, wds[c4*4+3], k1);
        }
        Ys[(size_t)p * NC + l] = y0 + y1;
        Ks[(size_t)p * NC + l] = (k0 + k1) + b1v;
    }
}

// ---------------------------------------------------------------------------
// Kernel D: distance matrix via bf16 MFMA. Block = 32 queries x 512 points
// (4 waves x 128 pts). A = points (global, coalesced b128), B = queries
// (LDS, pad-72). d = sqm + sqq - 2*dot, stored fp16 at D[q-qstart][m].
// ---------------------------------------------------------------------------
__global__ __launch_bounds__(256) void dist_kernel(const unsigned short* __restrict__ xbf,
                                                   const float* __restrict__ sqf,
                                                   unsigned short* __restrict__ D,
                                                   int qstart) {
    __shared__ unsigned short xq[32][72];
    __shared__ float sqq_l[32];
    const int t = threadIdx.x;
    const int w = t >> 6, l = t & 63;
    const int li = l & 15, g = l >> 4;
    const int qt32 = blockIdx.x >> 2, mq = blockIdx.x & 3;
    const int qbase = qstart + qt32 * 32;
    const int b = qbase >> 11;
    const size_t xrowb = (size_t)b * NP;

    {   // stage 32 query rows (bf16) + norms
        int row = t >> 3, seg = t & 7;
        uint4 vv = *reinterpret_cast<const uint4*>(xbf + (size_t)(qbase + row) * NC + seg * 8);
        *reinterpret_cast<uint4*>(&xq[row][seg * 8]) = vv;
        if (t < 32) sqq_l[t] = sqf[(size_t)qbase + t];
    }
    __syncthreads();

    short8v bq[2][2];
#pragma unroll
    for (int qt = 0; qt < 2; ++qt)
#pragma unroll
        for (int kk = 0; kk < 2; ++kk)
            bq[qt][kk] = *reinterpret_cast<const short8v*>(&xq[qt * 16 + li][kk * 32 + g * 8]);
    const float sqq0 = sqq_l[li], sqq1 = sqq_l[16 + li];

    const int mwbase = mq * 512 + w * 128;
#pragma unroll 2
    for (int mt = 0; mt < 8; ++mt) {
        const int m16 = mwbase + mt * 16;
        const unsigned short* arow = xbf + (xrowb + m16 + li) * NC + g * 8;
        short8v a0 = *reinterpret_cast<const short8v*>(arow);
        short8v a1 = *reinterpret_cast<const short8v*>(arow + 32);
        float4 sqm = *reinterpret_cast<const float4*>(sqf + xrowb + m16 + g * 4);
#pragma unroll
        for (int qt = 0; qt < 2; ++qt) {
            f32x4 acc = {0.f, 0.f, 0.f, 0.f};
            acc = __builtin_amdgcn_mfma_f32_16x16x32_bf16(a0, bq[qt][0], acc, 0, 0, 0);
            acc = __builtin_amdgcn_mfma_f32_16x16x32_bf16(a1, bq[qt][1], acc, 0, 0, 0);
            const float sqq = qt ? sqq1 : sqq0;
            ushort4 hv;
            hv.x = __half_as_ushort(__float2half(sqm.x + sqq - 2.f * acc[0]));
            hv.y = __half_as_ushort(__float2half(sqm.y + sqq - 2.f * acc[1]));
            hv.z = __half_as_ushort(__float2half(sqm.z + sqq - 2.f * acc[2]));
            hv.w = __half_as_ushort(__float2half(sqm.w + sqq - 2.f * acc[3]));
            *reinterpret_cast<ushort4*>(
                D + (size_t)(qbase - qstart + qt * 16 + li) * NP + m16 + g * 4) = hv;
        }
    }
}

// ---------------------------------------------------------------------------
// Kernel S: per-query top-RSEL superset via 2-level histogram radix-select.
// One wave per query (4/block). 1024-bin L1 on key>>6, 64-bin L2 gives the
// exact 16-bit threshold; ballot-compaction collects <=NCAND candidates.
// All LDS is wave-private: no __syncthreads needed.
// ---------------------------------------------------------------------------
__global__ __launch_bounds__(256) void select_kernel(const unsigned short* __restrict__ D,
                                                     unsigned short* __restrict__ cand,
                                                     int qstart) {
    __shared__ unsigned hist[4][1024];
    __shared__ unsigned hist2[4][64];
    __shared__ unsigned short cnd[4][NCAND];
    const int t = threadIdx.x, w = t >> 6, l = t & 63;
    const int qrel = blockIdx.x * 4 + w;
    const unsigned short* Drow = D + (size_t)qrel * NP;

    {   // zero wave-private LDS
        uint4 z = {0u, 0u, 0u, 0u};
#pragma unroll
        for (int i = 0; i < 4; ++i)
            *reinterpret_cast<uint4*>(&hist[w][l * 16 + i * 4]) = z;
        hist2[w][l] = 0u;
        cnd[w][l & 63] = 0xFFFFu;
        if (l < NCAND - 64) cnd[w][64 + l] = 0xFFFFu;
    }

    uint4 raw[4];
#pragma unroll
    for (int c = 0; c < 4; ++c)
        raw[c] = *reinterpret_cast<const uint4*>(Drow + c * 512 + l * 8);

    // L1 histogram
#pragma unroll
    for (int c = 0; c < 4; ++c) {
        unsigned wd[4] = {raw[c].x, raw[c].y, raw[c].z, raw[c].w};
#pragma unroll
        for (int j = 0; j < 4; ++j) {
            atomicAdd(&hist[w][h2key(wd[j] & 0xFFFFu) >> 6], 1u);
            atomicAdd(&hist[w][h2key(wd[j] >> 16) >> 6], 1u);
        }
    }

    // L1 scan: lane owns bins [16l, 16l+16)
    unsigned bins[16];
    unsigned s = 0;
#pragma unroll
    for (int i = 0; i < 4; ++i) {
        uint4 bv = *reinterpret_cast<const uint4*>(&hist[w][l * 16 + i * 4]);
        bins[i*4+0] = bv.x; bins[i*4+1] = bv.y; bins[i*4+2] = bv.z; bins[i*4+3] = bv.w;
        s += bv.x + bv.y + bv.z + bv.w;
    }
    unsigned inc = s;
#pragma unroll
    for (int off = 1; off < 64; off <<= 1) {
        unsigned tmp = __shfl_up(inc, off);
        if (l >= off) inc += tmp;
    }
    unsigned P = inc - s;
    bool flag = (P < RSEL) && (P + s >= RSEL);
    int src = __builtin_ctzll(__ballot(flag));
    unsigned T = 0, cumT = 0;
    if (flag) {
        unsigned cc = P; bool found = false;
#pragma unroll
        for (int i = 0; i < 16; ++i) {
            if (!found && cc + bins[i] >= RSEL) { T = l * 16 + i; cumT = cc; found = true; }
            cc += bins[i];
        }
    }
    T = __shfl((int)T, src); cumT = __shfl((int)cumT, src);

    // L2 histogram over bin T's low 6 bits
#pragma unroll
    for (int c = 0; c < 4; ++c) {
        unsigned wd[4] = {raw[c].x, raw[c].y, raw[c].z, raw[c].w};
#pragma unroll
        for (int j = 0; j < 4; ++j) {
            unsigned k0 = h2key(wd[j] & 0xFFFFu), k1 = h2key(wd[j] >> 16);
            if ((k0 >> 6) == T) atomicAdd(&hist2[w][k0 & 63], 1u);
            if ((k1 >> 6) == T) atomicAdd(&hist2[w][k1 & 63], 1u);
        }
    }
    unsigned h2 = hist2[w][l];
    unsigned inc2 = h2;
#pragma unroll
    for (int off = 1; off < 64; off <<= 1) {
        unsigned tmp = __shfl_up(inc2, off);
        if (l >= off) inc2 += tmp;
    }
    unsigned P2 = inc2 - h2;
    bool flag2 = (cumT + P2 < RSEL) && (cumT + P2 + h2 >= RSEL);
    int src2 = __builtin_ctzll(__ballot(flag2));
    const unsigned Kstar = (T << 6) | (unsigned)src2;

    // compaction: keep key <= Kstar (deterministic order, capped at NCAND)
    unsigned cnt = 0;
#pragma unroll
    for (int c = 0; c < 4; ++c) {
        unsigned wd[4] = {raw[c].x, raw[c].y, raw[c].z, raw[c].w};
#pragma unroll
        for (int j = 0; j < 4; ++j) {
#pragma unroll
            for (int hlf = 0; hlf < 2; ++hlf) {
                unsigned u16v = hlf ? (wd[j] >> 16) : (wd[j] & 0xFFFFu);
                bool keep = (h2key(u16v) <= Kstar);
                unsigned long long mkk = __ballot(keep);
                if (keep) {
                    unsigned pos = cnt + (unsigned)__popcll(mkk & ((1ull << l) - 1ull));
                    if (pos < NCAND)
                        cnd[w][pos] = (unsigned short)(c * 512 + l * 8 + j * 2 + hlf);
                }
                cnt += (unsigned)__popcll(mkk);
            }
        }
    }

    const size_t q = (size_t)(qstart + qrel);
    for (int i = l; i < NCAND; i += 64) cand[q * NCAND + i] = cnd[w][i];
}

// ---------------------------------------------------------------------------
// Kernel R: fp64 refinement — exact top-32 of <=80 candidates via all-pairs
// rank (order-free). One block (128 thr) per query.
// ---------------------------------------------------------------------------
__global__ __launch_bounds__(128) void refine_kernel(const float* __restrict__ x,
                                                     const unsigned short* __restrict__ cand,
                                                     unsigned short* __restrict__ idxout) {
    __shared__ double kd[128];
    __shared__ int km[128];
    __shared__ float qrow[64];
    const int t = threadIdx.x;
    const int q = blockIdx.x;
    const size_t bbase = (size_t)(q >> 11) << 11;

    if (t < 16)
        reinterpret_cast<float4*>(qrow)[t] =
            reinterpret_cast<const float4*>(x + (size_t)q * NC)[t];
    __syncthreads();

    int m = 0xFFFF;
    if (t < NCAND) m = cand[(size_t)q * NCAND + t];
    const bool valid = (m != 0xFFFF);
    const float* rowm = x + (bbase + (valid ? m : 0)) * NC;

    double dd = 0, ss = 0, uu = 0;
#pragma unroll
    for (int c4 = 0; c4 < 16; ++c4) {
        float4 a  = reinterpret_cast<const float4*>(qrow)[c4];
        float4 bb = reinterpret_cast<const float4*>(rowm)[c4];
        dd += (double)a.x*bb.x + (double)a.y*bb.y + (double)a.z*bb.z + (double)a.w*bb.w;
        ss += (double)a.x*a.x + (double)a.y*a.y + (double)a.z*a.z + (double)a.w*a.w;
        uu += (double)bb.x*bb.x + (double)bb.y*bb.y + (double)bb.z*bb.z + (double)bb.w*bb.w;
    }
    const double nd = valid ? (2.0 * dd - ss - uu) : -1e300;
    const int mym = valid ? m : 0x7FFFFFFF;
    kd[t] = nd; km[t] = mym;
    __syncthreads();

    int rank = 0;
#pragma unroll 8
    for (int j = 0; j < 128; ++j) {
        double oj = kd[j]; int mj = km[j];
        rank += (oj > nd || (oj == nd && mj < mym)) ? 1 : 0;
    }
    if (valid && rank < NK) idxout[(size_t)q * NK + rank] = (unsigned short)m;
}

// ---------------------------------------------------------------------------
// Kernel B: gather Ys[nbr]+Ks[i] -> LReLU -> bf16 h1 tile (LDS, pad-72) ->
// layer-2 via mfma_f32_16x16x32_bf16 -> BN+LReLU+max-over-k epilogue.
// ---------------------------------------------------------------------------
__global__ __launch_bounds__(256) void conv2_kernel(
    const float* __restrict__ Ys, const float* __restrict__ Ks,
    const unsigned short* __restrict__ W2bf,
    const float* __restrict__ g2, const float* __restrict__ b2,
    const unsigned short* __restrict__ idx16, float* __restrict__ out)
{
    __shared__ short w2l[128 * 72];
    __shared__ short h1l[4][32 * 72];

    const int t = threadIdx.x;
    const int w = t >> 6, l = t & 63;
    const int g = l >> 4, li = l & 15;
    const int p = blockIdx.x * 4 + w;
    const int b = p >> 11;
    const float invbn = 1.0f / sqrtf(1.0f + 1e-5f);

    {
        const int r = t >> 1, half = t & 1;
        const uint4* src = reinterpret_cast<const uint4*>(W2bf + (size_t)r * 64 + half * 32);
        uint4* dst = reinterpret_cast<uint4*>(&w2l[r * 72 + half * 32]);
#pragma unroll
        for (int i = 0; i < 4; ++i) dst[i] = src[i];
    }

    float g2r[8], b2r[8];
#pragma unroll
    for (int nt = 0; nt < 8; ++nt) {
        g2r[nt] = g2[nt * 16 + li] * invbn;
        b2r[nt] = b2[nt * 16 + li];
    }
    const float4 ksv = reinterpret_cast<const float4*>(Ks + (size_t)p * NC)[li];

    int jarr[8];
#pragma unroll
    for (int r2 = 0; r2 < 8; ++r2)
        jarr[r2] = idx16[(size_t)p * NK + r2 * 4 + g];

#pragma unroll
    for (int r2 = 0; r2 < 8; ++r2) {
        const int r = r2 * 4 + g;
        const float4 v = reinterpret_cast<const float4*>(
            Ys + ((size_t)(b << 11) + jarr[r2]) * NC)[li];
        float h0 = v.x + ksv.x; h0 = h0 > 0.f ? h0 : 0.01f * h0;
        float h1 = v.y + ksv.y; h1 = h1 > 0.f ? h1 : 0.01f * h1;
        float h2 = v.z + ksv.z; h2 = h2 > 0.f ? h2 : 0.01f * h2;
        float h3 = v.w + ksv.w; h3 = h3 > 0.f ? h3 : 0.01f * h3;
        ushort4 pk = { f2bf(h0), f2bf(h1), f2bf(h2), f2bf(h3) };
        *reinterpret_cast<ushort4*>(&h1l[w][r * 72 + li * 4]) = pk;
    }
    __syncthreads();

    short8v a[2][2];
#pragma unroll
    for (int mt2 = 0; mt2 < 2; ++mt2)
#pragma unroll
        for (int kt = 0; kt < 2; ++kt)
            a[mt2][kt] = *reinterpret_cast<const short8v*>(
                &h1l[w][(mt2 * 16 + li) * 72 + kt * 32 + g * 8]);

#pragma unroll 1
    for (int nt = 0; nt < 8; ++nt) {
        short8v b0 = *reinterpret_cast<const short8v*>(&w2l[(nt * 16 + li) * 72 + g * 8]);
        short8v b1 = *reinterpret_cast<const short8v*>(&w2l[(nt * 16 + li) * 72 + 32 + g * 8]);
        f32x4 acc0 = {0.f, 0.f, 0.f, 0.f};
        f32x4 acc1 = {0.f, 0.f, 0.f, 0.f};
        acc0 = __builtin_amdgcn_mfma_f32_16x16x32_bf16(a[0][0], b0, acc0, 0, 0, 0);
        acc0 = __builtin_amdgcn_mfma_f32_16x16x32_bf16(a[0][1], b1, acc0, 0, 0, 0);
        acc1 = __builtin_amdgcn_mfma_f32_16x16x32_bf16(a[1][0], b0, acc1, 0, 0, 0);
        acc1 = __builtin_amdgcn_mfma_f32_16x16x32_bf16(a[1][1], b1, acc1, 0, 0, 0);

        const float s2v = g2r[nt], c2v = b2r[nt];
        float mx = -FLT_MAX;
#pragma unroll
        for (int r = 0; r < 4; ++r) {
            float hA = acc0[r] * s2v + c2v; hA = hA > 0.f ? hA : 0.01f * hA;
            float hB = acc1[r] * s2v + c2v; hB = hB > 0.f ? hB : 0.01f * hB;
            mx = fmaxf(mx, fmaxf(hA, hB));
        }
        mx = fmaxf(mx, __shfl_xor(mx, 16));
        mx = fmaxf(mx, __shfl_xor(mx, 32));
        if (l < 16) out[(size_t)p * NO2 + nt * 16 + l] = mx;
    }
}

// ---------------------------------------------------------------------------
extern "C" void kernel_launch(void* const* d_in, const int* in_sizes, int n_in,
                              void* d_out, int out_size, void* d_ws, size_t ws_size,
                              hipStream_t stream) {
    const float* x  = (const float*)d_in[0];
    const float* W1 = (const float*)d_in[1];
    const float* g1 = (const float*)d_in[2];
    const float* b1 = (const float*)d_in[3];
    const float* W2 = (const float*)d_in[4];
    const float* g2 = (const float*)d_in[5];
    const float* b2 = (const float*)d_in[6];
    float* out = (float*)d_out;

    // workspace layout (fixed 14,237,696 B + D-chunk)
    char* ws = (char*)d_ws;
    unsigned short* xbf  = (unsigned short*)(ws);              // 2,097,152
    float*          sqf  = (float*)(ws + 2097152);             //    65,536
    unsigned short* candw= (unsigned short*)(ws + 2162688);    // 2,621,440
    unsigned short* idxw = (unsigned short*)(ws + 4784128);    // 1,048,576
    float*          Ysw  = (float*)(ws + 5832704);             // 4,194,304
    float*          Ksw  = (float*)(ws + 10027008);            // 4,194,304
    unsigned short* w2bfw= (unsigned short*)(ws + 14221312);   //    16,384
    unsigned short* Dw   = (unsigned short*)(ws + 14237696);   // qch*4KB

    size_t avail = ws_size > 14237696 ? ws_size - 14237696 : 0;
    int qch = NB * NP;                                         // 16384 queries
    while (qch > 64 && (size_t)qch * NP * 2 > avail) qch >>= 1;

    xcvt_sq_kernel<<<512, 256, 0, stream>>>(x, xbf, sqf);
    prep_kernel   <<<256, 256, 0, stream>>>(x, W1, g1, b1, W2, Ysw, Ksw, w2bfw);
    for (int qs = 0; qs < NB * NP; qs += qch) {
        dist_kernel  <<<qch / 8, 256, 0, stream>>>(xbf, sqf, Dw, qs);
        select_kernel<<<qch / 4, 256, 0, stream>>>(Dw, candw, qs);
    }
    refine_kernel<<<NB * NP,     128, 0, stream>>>(x, candw, idxw);
    conv2_kernel <<<NB * NP / 4, 256, 0, stream>>>(Ysw, Ksw, w2bfw, g2, b2, idxw, out);
}

// Round 5
// 163.088 us; speedup vs baseline: 12.2568x; 1.2327x over previous
//
#include <hip/hip_runtime.h>
#include <hip/hip_fp16.h>
#include <float.h>
#include <math.h>

// Problem constants (B=8, N=2048, C=64, k=32, out=[64,128])
#define NB    8
#define NP    2048
#define NC    64
#define NK    32
#define NCAND 80      // candidate buffer per query
#define RSEL  48      // rank-threshold for superset selection
#define NO2   128

typedef __attribute__((ext_vector_type(8))) short short8v;   // 8 bf16 (4 VGPRs)
typedef __attribute__((ext_vector_type(4))) float f32x4;

__device__ __forceinline__ unsigned short f2bf(float f) {    // RNE f32->bf16
    unsigned u = __float_as_uint(f);
    return (unsigned short)((u + 0x7fffu + ((u >> 16) & 1u)) >> 16);
}

// sortable-u16 key from raw fp16 bits (ascending distance -> ascending key)
__device__ __forceinline__ unsigned h2key(unsigned u) {
    return (u & 0x8000u) ? (u ^ 0xFFFFu) : (u | 0x8000u);
}

// ---------------------------------------------------------------------------
// Kernel 0: x -> bf16 copy + fp32 norms (ranking) + fp64 norms (refine).
// 8 threads/point.
// ---------------------------------------------------------------------------
__global__ __launch_bounds__(256) void xcvt_sq_kernel(const float* __restrict__ x,
                                                      unsigned short* __restrict__ xbf,
                                                      float* __restrict__ sqf,
                                                      double* __restrict__ sq64) {
    int gid = blockIdx.x * 256 + threadIdx.x;
    int p = gid >> 3, c8 = (gid & 7) * 8;
    const float4* src = reinterpret_cast<const float4*>(x + (size_t)p * NC + c8);
    float4 v0 = src[0], v1 = src[1];
    ushort4 pk0 = { f2bf(v0.x), f2bf(v0.y), f2bf(v0.z), f2bf(v0.w) };
    ushort4 pk1 = { f2bf(v1.x), f2bf(v1.y), f2bf(v1.z), f2bf(v1.w) };
    ushort4* dst = reinterpret_cast<ushort4*>(xbf + (size_t)p * NC + c8);
    dst[0] = pk0; dst[1] = pk1;
    double s = (double)v0.x*v0.x + (double)v0.y*v0.y + (double)v0.z*v0.z + (double)v0.w*v0.w
             + (double)v1.x*v1.x + (double)v1.y*v1.y + (double)v1.z*v1.z + (double)v1.w*v1.w;
    s += __shfl_xor(s, 1); s += __shfl_xor(s, 2); s += __shfl_xor(s, 4);
    if ((threadIdx.x & 7) == 0) { sq64[p] = s; sqf[p] = (float)s; }
}

// ---------------------------------------------------------------------------
// Kernel P: prep — Ys = (x.W1a^T)*s1, Ks = (x.(W1b-W1a)^T)*s1 + b1 (fp32),
// plus W2 packed to bf16. One wave per 16 points; lane = output channel.
// ---------------------------------------------------------------------------
__global__ __launch_bounds__(256) void prep_kernel(
    const float* __restrict__ x, const float* __restrict__ W1,
    const float* __restrict__ g1, const float* __restrict__ b1,
    const float* __restrict__ W2,
    float* __restrict__ Ys, float* __restrict__ Ks,
    unsigned short* __restrict__ W2bf)
{
    const int t = threadIdx.x;
    const int w = t >> 6, l = t & 63;
    const float invbn = 1.0f / sqrtf(1.0f + 1e-5f);

    if (blockIdx.x == 0 && t < 128) {
        const float4* src = reinterpret_cast<const float4*>(W2 + (size_t)t * 64);
        ushort4* dst = reinterpret_cast<ushort4*>(W2bf + (size_t)t * 64);
#pragma unroll
        for (int i = 0; i < 16; ++i) {
            float4 v = src[i];
            ushort4 pk = { f2bf(v.x), f2bf(v.y), f2bf(v.z), f2bf(v.w) };
            dst[i] = pk;
        }
    }

    float was[64], wds[64];
    const float s1v = g1[l] * invbn;
    const float b1v = b1[l];
#pragma unroll
    for (int c4 = 0; c4 < 16; ++c4) {
        float4 lo = reinterpret_cast<const float4*>(W1 + (size_t)l * 128)[c4];
        float4 hi = reinterpret_cast<const float4*>(W1 + (size_t)l * 128 + 64)[c4];
        was[c4*4+0] = lo.x * s1v; was[c4*4+1] = lo.y * s1v;
        was[c4*4+2] = lo.z * s1v; was[c4*4+3] = lo.w * s1v;
        wds[c4*4+0] = (hi.x - lo.x) * s1v; wds[c4*4+1] = (hi.y - lo.y) * s1v;
        wds[c4*4+2] = (hi.z - lo.z) * s1v; wds[c4*4+3] = (hi.w - lo.w) * s1v;
    }

    const int pbase = (blockIdx.x * 4 + w) * 16;
#pragma unroll 1
    for (int i = 0; i < 16; ++i) {
        const int p = pbase + i;
        const float* xr = x + (size_t)p * NC;
        float y0 = 0.f, y1 = 0.f, k0 = 0.f, k1 = 0.f;
#pragma unroll
        for (int c4 = 0; c4 < 16; ++c4) {
            float4 v = reinterpret_cast<const float4*>(xr)[c4];
            y0 = fmaf(v.x, was[c4*4+0], y0); y1 = fmaf(v.y, was[c4*4+1], y1);
            y0 = fmaf(v.z, was[c4*4+2], y0); y1 = fmaf(v.w, was[c4*4+3], y1);
            k0 = fmaf(v.x, wds[c4*4+0], k0); k1 = fmaf(v.y, wds[c4*4+1], k1);
            k0 = fmaf(v.z, wds[c4*4+2], k0); k1 = fmaf(v.w, wds[c4*4+3], k1);
        }
        Ys[(size_t)p * NC + l] = y0 + y1;
        Ks[(size_t)p * NC + l] = (k0 + k1) + b1v;
    }
}

// ---------------------------------------------------------------------------
// Kernel D: distance matrix via bf16 MFMA. Block = 32 queries x 512 points
// (4 waves x 128 pts). A = points (global, coalesced b128), B = queries
// (LDS, pad-72). d = sqm + sqq - 2*dot, stored fp16 at D[q-qstart][m].
// ---------------------------------------------------------------------------
__global__ __launch_bounds__(256) void dist_kernel(const unsigned short* __restrict__ xbf,
                                                   const float* __restrict__ sqf,
                                                   unsigned short* __restrict__ D,
                                                   int qstart) {
    __shared__ unsigned short xq[32][72];
    __shared__ float sqq_l[32];
    const int t = threadIdx.x;
    const int w = t >> 6, l = t & 63;
    const int li = l & 15, g = l >> 4;
    const int qt32 = blockIdx.x >> 2, mq = blockIdx.x & 3;
    const int qbase = qstart + qt32 * 32;
    const int b = qbase >> 11;
    const size_t xrowb = (size_t)b * NP;

    {   // stage 32 query rows (bf16) + norms
        int row = t >> 3, seg = t & 7;
        uint4 vv = *reinterpret_cast<const uint4*>(xbf + (size_t)(qbase + row) * NC + seg * 8);
        *reinterpret_cast<uint4*>(&xq[row][seg * 8]) = vv;
        if (t < 32) sqq_l[t] = sqf[(size_t)qbase + t];
    }
    __syncthreads();

    short8v bq[2][2];
#pragma unroll
    for (int qt = 0; qt < 2; ++qt)
#pragma unroll
        for (int kk = 0; kk < 2; ++kk)
            bq[qt][kk] = *reinterpret_cast<const short8v*>(&xq[qt * 16 + li][kk * 32 + g * 8]);
    const float sqq0 = sqq_l[li], sqq1 = sqq_l[16 + li];

    const int mwbase = mq * 512 + w * 128;
#pragma unroll 2
    for (int mt = 0; mt < 8; ++mt) {
        const int m16 = mwbase + mt * 16;
        const unsigned short* arow = xbf + (xrowb + m16 + li) * NC + g * 8;
        short8v a0 = *reinterpret_cast<const short8v*>(arow);
        short8v a1 = *reinterpret_cast<const short8v*>(arow + 32);
        float4 sqm = *reinterpret_cast<const float4*>(sqf + xrowb + m16 + g * 4);
#pragma unroll
        for (int qt = 0; qt < 2; ++qt) {
            f32x4 acc = {0.f, 0.f, 0.f, 0.f};
            acc = __builtin_amdgcn_mfma_f32_16x16x32_bf16(a0, bq[qt][0], acc, 0, 0, 0);
            acc = __builtin_amdgcn_mfma_f32_16x16x32_bf16(a1, bq[qt][1], acc, 0, 0, 0);
            const float sqq = qt ? sqq1 : sqq0;
            ushort4 hv;
            hv.x = __half_as_ushort(__float2half(sqm.x + sqq - 2.f * acc[0]));
            hv.y = __half_as_ushort(__float2half(sqm.y + sqq - 2.f * acc[1]));
            hv.z = __half_as_ushort(__float2half(sqm.z + sqq - 2.f * acc[2]));
            hv.w = __half_as_ushort(__float2half(sqm.w + sqq - 2.f * acc[3]));
            *reinterpret_cast<ushort4*>(
                D + (size_t)(qbase - qstart + qt * 16 + li) * NP + m16 + g * 4) = hv;
        }
    }
}

// ---------------------------------------------------------------------------
// Kernel S: per-query top-RSEL superset via 2-level histogram radix-select.
// One wave per query (4/block). Also stores the kept-count for refine.
// ---------------------------------------------------------------------------
__global__ __launch_bounds__(256) void select_kernel(const unsigned short* __restrict__ D,
                                                     unsigned short* __restrict__ cand,
                                                     unsigned short* __restrict__ ccnt,
                                                     int qstart) {
    __shared__ unsigned hist[4][1024];
    __shared__ unsigned hist2[4][64];
    __shared__ unsigned short cnd[4][NCAND];
    const int t = threadIdx.x, w = t >> 6, l = t & 63;
    const int qrel = blockIdx.x * 4 + w;
    const unsigned short* Drow = D + (size_t)qrel * NP;

    {   // zero wave-private LDS
        uint4 z = {0u, 0u, 0u, 0u};
#pragma unroll
        for (int i = 0; i < 4; ++i)
            *reinterpret_cast<uint4*>(&hist[w][l * 16 + i * 4]) = z;
        hist2[w][l] = 0u;
        cnd[w][l & 63] = 0xFFFFu;
        if (l < NCAND - 64) cnd[w][64 + l] = 0xFFFFu;
    }

    uint4 raw[4];
#pragma unroll
    for (int c = 0; c < 4; ++c)
        raw[c] = *reinterpret_cast<const uint4*>(Drow + c * 512 + l * 8);

    // L1 histogram
#pragma unroll
    for (int c = 0; c < 4; ++c) {
        unsigned wd[4] = {raw[c].x, raw[c].y, raw[c].z, raw[c].w};
#pragma unroll
        for (int j = 0; j < 4; ++j) {
            atomicAdd(&hist[w][h2key(wd[j] & 0xFFFFu) >> 6], 1u);
            atomicAdd(&hist[w][h2key(wd[j] >> 16) >> 6], 1u);
        }
    }

    // L1 scan: lane owns bins [16l, 16l+16)
    unsigned bins[16];
    unsigned s = 0;
#pragma unroll
    for (int i = 0; i < 4; ++i) {
        uint4 bv = *reinterpret_cast<const uint4*>(&hist[w][l * 16 + i * 4]);
        bins[i*4+0] = bv.x; bins[i*4+1] = bv.y; bins[i*4+2] = bv.z; bins[i*4+3] = bv.w;
        s += bv.x + bv.y + bv.z + bv.w;
    }
    unsigned inc = s;
#pragma unroll
    for (int off = 1; off < 64; off <<= 1) {
        unsigned tmp = __shfl_up(inc, off);
        if (l >= off) inc += tmp;
    }
    unsigned P = inc - s;
    bool flag = (P < RSEL) && (P + s >= RSEL);
    int src = __builtin_ctzll(__ballot(flag));
    unsigned T = 0, cumT = 0;
    if (flag) {
        unsigned cc = P; bool found = false;
#pragma unroll
        for (int i = 0; i < 16; ++i) {
            if (!found && cc + bins[i] >= RSEL) { T = l * 16 + i; cumT = cc; found = true; }
            cc += bins[i];
        }
    }
    T = __shfl((int)T, src); cumT = __shfl((int)cumT, src);

    // L2 histogram over bin T's low 6 bits
#pragma unroll
    for (int c = 0; c < 4; ++c) {
        unsigned wd[4] = {raw[c].x, raw[c].y, raw[c].z, raw[c].w};
#pragma unroll
        for (int j = 0; j < 4; ++j) {
            unsigned k0 = h2key(wd[j] & 0xFFFFu), k1 = h2key(wd[j] >> 16);
            if ((k0 >> 6) == T) atomicAdd(&hist2[w][k0 & 63], 1u);
            if ((k1 >> 6) == T) atomicAdd(&hist2[w][k1 & 63], 1u);
        }
    }
    unsigned h2 = hist2[w][l];
    unsigned inc2 = h2;
#pragma unroll
    for (int off = 1; off < 64; off <<= 1) {
        unsigned tmp = __shfl_up(inc2, off);
        if (l >= off) inc2 += tmp;
    }
    unsigned P2 = inc2 - h2;
    bool flag2 = (cumT + P2 < RSEL) && (cumT + P2 + h2 >= RSEL);
    int src2 = __builtin_ctzll(__ballot(flag2));
    const unsigned Kstar = (T << 6) | (unsigned)src2;

    // compaction: keep key <= Kstar (deterministic order, capped at NCAND)
    unsigned cnt = 0;
#pragma unroll
    for (int c = 0; c < 4; ++c) {
        unsigned wd[4] = {raw[c].x, raw[c].y, raw[c].z, raw[c].w};
#pragma unroll
        for (int j = 0; j < 4; ++j) {
#pragma unroll
            for (int hlf = 0; hlf < 2; ++hlf) {
                unsigned u16v = hlf ? (wd[j] >> 16) : (wd[j] & 0xFFFFu);
                bool keep = (h2key(u16v) <= Kstar);
                unsigned long long mkk = __ballot(keep);
                if (keep) {
                    unsigned pos = cnt + (unsigned)__popcll(mkk & ((1ull << l) - 1ull));
                    if (pos < NCAND)
                        cnd[w][pos] = (unsigned short)(c * 512 + l * 8 + j * 2 + hlf);
                }
                cnt += (unsigned)__popcll(mkk);
            }
        }
    }

    const size_t q = (size_t)(qstart + qrel);
    if (l == 0) ccnt[q] = (unsigned short)(cnt < NCAND ? cnt : NCAND);
    for (int i = l; i < NCAND; i += 64) cand[q * NCAND + i] = cnd[w][i];
}

// ---------------------------------------------------------------------------
// Kernel R: fp64 refinement — exact top-32 of the cnt (<=80) candidates via
// all-pairs rank (order-free). key = |m|^2 - 2 q.m (si constant per query).
// One block (128 thr) per query; rank loop runs cnt iterations only.
// ---------------------------------------------------------------------------
__global__ __launch_bounds__(128) void refine_kernel(const float* __restrict__ x,
                                                     const double* __restrict__ sq64,
                                                     const unsigned short* __restrict__ cand,
                                                     const unsigned short* __restrict__ ccnt,
                                                     unsigned short* __restrict__ idxout) {
    __shared__ float qrow[64];
    __shared__ double2 kd2[128];   // .x = key (ascending), .y = idx as double
    const int t = threadIdx.x;
    const int q = blockIdx.x;
    const size_t bbase = (size_t)(q >> 11) << 11;

    if (t < 16)
        reinterpret_cast<float4*>(qrow)[t] =
            reinterpret_cast<const float4*>(x + (size_t)q * NC)[t];
    __syncthreads();

    const int cnt = ccnt[q];                  // wave-uniform
    int m = 0;
    if (t < NCAND) m = cand[(size_t)q * NCAND + t];
    const bool valid = (t < cnt);
    m = valid ? m : 0;
    const float* rowm = x + (bbase + m) * NC;

    double dot = 0;
#pragma unroll
    for (int c4 = 0; c4 < 16; ++c4) {
        float4 a  = reinterpret_cast<const float4*>(qrow)[c4];   // LDS broadcast
        float4 bb = reinterpret_cast<const float4*>(rowm)[c4];
        dot += (double)a.x * bb.x + (double)a.y * bb.y
             + (double)a.z * bb.z + (double)a.w * bb.w;
    }
    const double key = valid ? (sq64[bbase + m] - 2.0 * dot) : 1e300;
    const double mid = (double)m;
    kd2[t] = make_double2(key, mid);
    __syncthreads();

    int rank = 0;
#pragma unroll 4
    for (int j = 0; j < cnt; ++j) {
        double2 o = kd2[j];
        rank += (o.x < key || (o.x == key && o.y < mid)) ? 1 : 0;
    }
    if (valid && rank < NK) idxout[(size_t)q * NK + rank] = (unsigned short)m;
}

// ---------------------------------------------------------------------------
// Kernel B: gather Ys[nbr]+Ks[i] -> LReLU -> bf16 h1 tile (LDS, pad-72) ->
// layer-2 via mfma_f32_16x16x32_bf16 -> BN+LReLU+max-over-k epilogue.
// ---------------------------------------------------------------------------
__global__ __launch_bounds__(256) void conv2_kernel(
    const float* __restrict__ Ys, const float* __restrict__ Ks,
    const unsigned short* __restrict__ W2bf,
    const float* __restrict__ g2, const float* __restrict__ b2,
    const unsigned short* __restrict__ idx16, float* __restrict__ out)
{
    __shared__ short w2l[128 * 72];
    __shared__ short h1l[4][32 * 72];

    const int t = threadIdx.x;
    const int w = t >> 6, l = t & 63;
    const int g = l >> 4, li = l & 15;
    const int p = blockIdx.x * 4 + w;
    const int b = p >> 11;
    const float invbn = 1.0f / sqrtf(1.0f + 1e-5f);

    {
        const int r = t >> 1, half = t & 1;
        const uint4* src = reinterpret_cast<const uint4*>(W2bf + (size_t)r * 64 + half * 32);
        uint4* dst = reinterpret_cast<uint4*>(&w2l[r * 72 + half * 32]);
#pragma unroll
        for (int i = 0; i < 4; ++i) dst[i] = src[i];
    }

    float g2r[8], b2r[8];
#pragma unroll
    for (int nt = 0; nt < 8; ++nt) {
        g2r[nt] = g2[nt * 16 + li] * invbn;
        b2r[nt] = b2[nt * 16 + li];
    }
    const float4 ksv = reinterpret_cast<const float4*>(Ks + (size_t)p * NC)[li];

    int jarr[8];
#pragma unroll
    for (int r2 = 0; r2 < 8; ++r2)
        jarr[r2] = idx16[(size_t)p * NK + r2 * 4 + g];

#pragma unroll
    for (int r2 = 0; r2 < 8; ++r2) {
        const int r = r2 * 4 + g;
        const float4 v = reinterpret_cast<const float4*>(
            Ys + ((size_t)(b << 11) + jarr[r2]) * NC)[li];
        float h0 = v.x + ksv.x; h0 = h0 > 0.f ? h0 : 0.01f * h0;
        float h1 = v.y + ksv.y; h1 = h1 > 0.f ? h1 : 0.01f * h1;
        float h2 = v.z + ksv.z; h2 = h2 > 0.f ? h2 : 0.01f * h2;
        float h3 = v.w + ksv.w; h3 = h3 > 0.f ? h3 : 0.01f * h3;
        ushort4 pk = { f2bf(h0), f2bf(h1), f2bf(h2), f2bf(h3) };
        *reinterpret_cast<ushort4*>(&h1l[w][r * 72 + li * 4]) = pk;
    }
    __syncthreads();

    short8v a[2][2];
#pragma unroll
    for (int mt2 = 0; mt2 < 2; ++mt2)
#pragma unroll
        for (int kt = 0; kt < 2; ++kt)
            a[mt2][kt] = *reinterpret_cast<const short8v*>(
                &h1l[w][(mt2 * 16 + li) * 72 + kt * 32 + g * 8]);

#pragma unroll 1
    for (int nt = 0; nt < 8; ++nt) {
        short8v b0 = *reinterpret_cast<const short8v*>(&w2l[(nt * 16 + li) * 72 + g * 8]);
        short8v b1 = *reinterpret_cast<const short8v*>(&w2l[(nt * 16 + li) * 72 + 32 + g * 8]);
        f32x4 acc0 = {0.f, 0.f, 0.f, 0.f};
        f32x4 acc1 = {0.f, 0.f, 0.f, 0.f};
        acc0 = __builtin_amdgcn_mfma_f32_16x16x32_bf16(a[0][0], b0, acc0, 0, 0, 0);
        acc0 = __builtin_amdgcn_mfma_f32_16x16x32_bf16(a[0][1], b1, acc0, 0, 0, 0);
        acc1 = __builtin_amdgcn_mfma_f32_16x16x32_bf16(a[1][0], b0, acc1, 0, 0, 0);
        acc1 = __builtin_amdgcn_mfma_f32_16x16x32_bf16(a[1][1], b1, acc1, 0, 0, 0);

        const float s2v = g2r[nt], c2v = b2r[nt];
        float mx = -FLT_MAX;
#pragma unroll
        for (int r = 0; r < 4; ++r) {
            float hA = acc0[r] * s2v + c2v; hA = hA > 0.f ? hA : 0.01f * hA;
            float hB = acc1[r] * s2v + c2v; hB = hB > 0.f ? hB : 0.01f * hB;
            mx = fmaxf(mx, fmaxf(hA, hB));
        }
        mx = fmaxf(mx, __shfl_xor(mx, 16));
        mx = fmaxf(mx, __shfl_xor(mx, 32));
        if (l < 16) out[(size_t)p * NO2 + nt * 16 + l] = mx;
    }
}

// ---------------------------------------------------------------------------
extern "C" void kernel_launch(void* const* d_in, const int* in_sizes, int n_in,
                              void* d_out, int out_size, void* d_ws, size_t ws_size,
                              hipStream_t stream) {
    const float* x  = (const float*)d_in[0];
    const float* W1 = (const float*)d_in[1];
    const float* g1 = (const float*)d_in[2];
    const float* b1 = (const float*)d_in[3];
    const float* W2 = (const float*)d_in[4];
    const float* g2 = (const float*)d_in[5];
    const float* b2 = (const float*)d_in[6];
    float* out = (float*)d_out;

    // workspace layout (fixed 14,401,536 B + D-chunk)
    char* ws = (char*)d_ws;
    unsigned short* xbf  = (unsigned short*)(ws);              // 2,097,152
    float*          sqf  = (float*)(ws + 2097152);             //    65,536
    double*         sq64 = (double*)(ws + 2162688);            //   131,072
    unsigned short* candw= (unsigned short*)(ws + 2293760);    // 2,621,440
    unsigned short* cntw = (unsigned short*)(ws + 4915200);    //    32,768
    unsigned short* idxw = (unsigned short*)(ws + 4947968);    // 1,048,576
    float*          Ysw  = (float*)(ws + 5996544);             // 4,194,304
    float*          Ksw  = (float*)(ws + 10190848);            // 4,194,304
    unsigned short* w2bfw= (unsigned short*)(ws + 14385152);   //    16,384
    unsigned short* Dw   = (unsigned short*)(ws + 14401536);   // qch*4KB

    size_t avail = ws_size > 14401536 ? ws_size - 14401536 : 0;
    int qch = NB * NP;                                         // 16384 queries
    while (qch > 64 && (size_t)qch * NP * 2 > avail) qch >>= 1;

    xcvt_sq_kernel<<<512, 256, 0, stream>>>(x, xbf, sqf, sq64);
    prep_kernel   <<<256, 256, 0, stream>>>(x, W1, g1, b1, W2, Ysw, Ksw, w2bfw);
    for (int qs = 0; qs < NB * NP; qs += qch) {
        dist_kernel  <<<qch / 8, 256, 0, stream>>>(xbf, sqf, Dw, qs);
        select_kernel<<<qch / 4, 256, 0, stream>>>(Dw, candw, cntw, qs);
    }
    refine_kernel<<<NB * NP,     128, 0, stream>>>(x, sq64, candw, cntw, idxw);
    conv2_kernel <<<NB * NP / 4, 256, 0, stream>>>(Ysw, Ksw, w2bfw, g2, b2, idxw, out);
}